// Round 1
// baseline (4519.925 us; speedup 1.0000x reference)
//
#include <hip/hip_runtime.h>
#include <math.h>
#include <stdint.h>

#define NR_ 16384
#define NP2_ 40000
#define NM_ 30000
#define NE_ 200000
#define EMB_ 1024
#define HID_ 256
#define OUTD_ 128

// ---------------- small utility kernels ----------------
__global__ void k_zero_i32(int* p, int n) {
    int i = blockIdx.x * 256 + threadIdx.x;
    if (i < n) p[i] = 0;
}
__global__ void k_copy_i32(int* d, const int* s, int n) {
    int i = blockIdx.x * 256 + threadIdx.x;
    if (i < n) d[i] = s[i];
}
__global__ void k_deg(const int* __restrict__ dst, int n, int* __restrict__ deg) {
    int i = blockIdx.x * 256 + threadIdx.x;
    if (i < n) atomicAdd(&deg[dst[i]], 1);
}
// single-block exclusive scan (n up to ~40001), writes offs[0..n]
__global__ void k_scan(const int* __restrict__ deg, int* __restrict__ offs, int n) {
    __shared__ int buf[2][1024];
    __shared__ int carry;
    if (threadIdx.x == 0) carry = 0;
    __syncthreads();
    for (int base = 0; base < n; base += 1024) {
        int i = base + threadIdx.x;
        int v = (i < n) ? deg[i] : 0;
        int cur = 0;
        buf[0][threadIdx.x] = v;
        __syncthreads();
        for (int s = 1; s < 1024; s <<= 1) {
            int t = buf[cur][threadIdx.x];
            if (threadIdx.x >= (unsigned)s) t += buf[cur][threadIdx.x - s];
            buf[cur ^ 1][threadIdx.x] = t;
            cur ^= 1;
            __syncthreads();
        }
        int incl = buf[cur][threadIdx.x];
        if (i < n) offs[i] = carry + incl - v;
        __syncthreads();
        if (threadIdx.x == 1023) carry += incl;
        __syncthreads();
    }
    if (threadIdx.x == 0) offs[n] = carry;
}
__global__ void k_scatter(const int* __restrict__ src, const int* __restrict__ dst, int n,
                          int* __restrict__ cur, int* __restrict__ csr) {
    int i = blockIdx.x * 256 + threadIdx.x;
    if (i < n) {
        int d = dst[i];
        int p = atomicAdd(&cur[d], 1);
        csr[p] = src[i];
    }
}
__global__ void k_addw(const float* __restrict__ a, const float* __restrict__ b,
                       float* __restrict__ o, int n) {
    int i = blockIdx.x * 256 + threadIdx.x;
    if (i < n) o[i] = a[i] + b[i];
}

// ---------------- f32 GEMM: C[M,N] = A[M,K] @ B[K,N] ----------------
// 64x64 tile, 256 threads, 4x4 micro-tile, K-step 16.
__global__ __launch_bounds__(256) void k_gemm(const float* __restrict__ A,
                                              const float* __restrict__ B,
                                              float* __restrict__ C,
                                              int M, int N, int K) {
    __shared__ float As[64][17];   // [m][k], padded to kill read conflicts
    __shared__ float Bs[16][64];   // [k][n]
    int tid = threadIdx.x;
    int tx = tid & 15, ty = tid >> 4;
    int bm = blockIdx.x * 64, bn = blockIdx.y * 64;
    float acc[4][4] = {};
    for (int k0 = 0; k0 < K; k0 += 16) {
        #pragma unroll
        for (int r = 0; r < 4; ++r) {
            int m = ty + r * 16;
            int gm = bm + m;
            As[m][tx] = (gm < M) ? A[(size_t)gm * K + k0 + tx] : 0.f;
        }
        {
            const float* bp = &B[(size_t)(k0 + ty) * N + bn + tx * 4];
            float4 v = *(const float4*)bp;
            *(float4*)&Bs[ty][tx * 4] = v;
        }
        __syncthreads();
        #pragma unroll
        for (int k = 0; k < 16; ++k) {
            float a[4], b[4];
            #pragma unroll
            for (int i = 0; i < 4; ++i) a[i] = As[ty * 4 + i][k];
            #pragma unroll
            for (int j = 0; j < 4; ++j) b[j] = Bs[k][tx * 4 + j];
            #pragma unroll
            for (int i = 0; i < 4; ++i)
                #pragma unroll
                for (int j = 0; j < 4; ++j) acc[i][j] += a[i] * b[j];
        }
        __syncthreads();
    }
    #pragma unroll
    for (int i = 0; i < 4; ++i) {
        int gm = bm + ty * 4 + i;
        if (gm < M) {
            float4 v = make_float4(acc[i][0], acc[i][1], acc[i][2], acc[i][3]);
            *(float4*)&C[(size_t)gm * N + bn + tx * 4] = v;
        }
    }
}

// ---------------- CSR mean-aggregate (+= mean + bias) ----------------
__global__ __launch_bounds__(256) void k_aggregate(const int* __restrict__ offs,
                                                   const int* __restrict__ csr,
                                                   const float* __restrict__ proj,
                                                   const float* __restrict__ bias,
                                                   float* __restrict__ outx, int n_dst) {
    int node = blockIdx.x;
    int t = threadIdx.x;
    int beg = offs[node], end = offs[node + 1];
    __shared__ int idx[256];
    float sum = 0.f;
    for (int b = beg; b < end; b += 256) {
        int cnt = min(256, end - b);
        if (t < cnt) idx[t] = csr[b + t];
        __syncthreads();
        for (int e = 0; e < cnt; ++e) sum += proj[(size_t)idx[e] * HID_ + t];
        __syncthreads();
    }
    float c = (float)(end - beg);
    outx[(size_t)node * HID_ + t] += sum / fmaxf(c, 1.f) + bias[t];
}

// ---------------- fused final: reaction proj + per-type node proj + cosine ----------------
__global__ __launch_bounds__(128) void k_final(const float* __restrict__ xr,
                                               const float* __restrict__ Wre,
                                               const float* __restrict__ bre,
                                               const float* __restrict__ notes,
                                               const int* __restrict__ types,
                                               const float* __restrict__ Wn,
                                               const float* __restrict__ bn,
                                               float* __restrict__ out) {
    int i = blockIdx.x;
    int j = threadIdx.x;  // 128
    __shared__ float xs[EMB_];
    __shared__ float rs[HID_];
    for (int k = j; k < EMB_; k += 128) xs[k] = notes[(size_t)i * EMB_ + k];
    for (int k = j; k < HID_; k += 128) rs[k] = xr[(size_t)i * HID_ + k];
    __syncthreads();
    float r = bre[j];
    #pragma unroll 4
    for (int k = 0; k < HID_; ++k) r += rs[k] * Wre[k * OUTD_ + j];
    int t = types[i];
    const float* W = Wn + (size_t)t * EMB_ * OUTD_;
    float nn = bn[t * OUTD_ + j];
    #pragma unroll 4
    for (int k = 0; k < EMB_; ++k) nn += xs[k] * W[k * OUTD_ + j];
    float v_num = r * nn, v_d1 = r * r, v_d2 = nn * nn;
    for (int s = 32; s > 0; s >>= 1) {
        v_num += __shfl_down(v_num, s);
        v_d1  += __shfl_down(v_d1, s);
        v_d2  += __shfl_down(v_d2, s);
    }
    __shared__ float sm[3][2];
    int wid = j >> 6, lane = j & 63;
    if (lane == 0) { sm[0][wid] = v_num; sm[1][wid] = v_d1; sm[2][wid] = v_d2; }
    __syncthreads();
    if (j == 0) {
        float num = sm[0][0] + sm[0][1];
        float d1 = sm[1][0] + sm[1][1];
        float d2 = sm[2][0] + sm[2][1];
        out[i] = (num / fmaxf(sqrtf(d1) * sqrtf(d2), 1e-8f) + 1.f) * 0.5f;
    }
}

extern "C" void kernel_launch(void* const* d_in, const int* in_sizes, int n_in,
                              void* d_out, int out_size, void* d_ws, size_t ws_size,
                              hipStream_t stream) {
    const float* x_r0 = (const float*)d_in[0];
    const float* x_p0 = (const float*)d_in[1];
    const float* x_m0 = (const float*)d_in[2];
    const int* es[4][2] = {
        {(const int*)d_in[3], (const int*)d_in[4]},   // p2r
        {(const int*)d_in[5], (const int*)d_in[6]},   // m2r
        {(const int*)d_in[7], (const int*)d_in[8]},   // r2p
        {(const int*)d_in[9], (const int*)d_in[10]},  // r2m
    };
    const float* notes = (const float*)d_in[11];
    const int* types = (const int*)d_in[12];
    const float* Wl0 = (const float*)d_in[13];
    const float* Wr0 = (const float*)d_in[14];
    const float* bl0 = (const float*)d_in[15];
    const float* WlL = (const float*)d_in[16];
    const float* WrL = (const float*)d_in[17];
    const float* blL = (const float*)d_in[18];
    const float* Wre = (const float*)d_in[19];
    const float* bre = (const float*)d_in[20];
    const float* Wn  = (const float*)d_in[21];
    const float* bn  = (const float*)d_in[22];
    float* out = (float*)d_out;

    // ---- workspace carve ----
    uintptr_t base = (uintptr_t)d_ws;
    auto alloc = [&](size_t bytes) -> void* {
        uintptr_t p = (base + 255) & ~(uintptr_t)255;
        base = p + bytes;
        return (void*)p;
    };
    const size_t NX = (size_t)(NR_ + NP2_ + NM_) * HID_;
    float* xA = (float*)alloc(NX * 4);
    float* xB = (float*)alloc(NX * 4);
    float* proj = (float*)alloc((size_t)NP2_ * HID_ * 4);
    float* wc = (float*)alloc((size_t)EMB_ * HID_ * 4);
    int nd[4] = {NR_, NR_, NP2_, NM_};
    int *offs[4], *cur[4], *csr[4];
    for (int t = 0; t < 4; ++t) {
        offs[t] = (int*)alloc(((size_t)nd[t] + 1) * 4);
        cur[t]  = (int*)alloc((size_t)nd[t] * 4);
        csr[t]  = (int*)alloc((size_t)NE_ * 4);
    }

    // ---- CSR build (per call; edges are inputs) ----
    for (int t = 0; t < 4; ++t) {
        int n = nd[t];
        k_zero_i32<<<(n + 255) / 256, 256, 0, stream>>>(cur[t], n);
        k_deg<<<(NE_ + 255) / 256, 256, 0, stream>>>(es[t][1], NE_, cur[t]);
        k_scan<<<1, 1024, 0, stream>>>(cur[t], offs[t], n);
        k_copy_i32<<<(n + 255) / 256, 256, 0, stream>>>(cur[t], offs[t], n);
        k_scatter<<<(NE_ + 255) / 256, 256, 0, stream>>>(es[t][0], es[t][1], NE_, cur[t], csr[t]);
    }

    auto gemm = [&](const float* A, const float* B, float* C, int M, int N, int K) {
        dim3 g((M + 63) / 64, N / 64);
        k_gemm<<<g, 256, 0, stream>>>(A, B, C, M, N, K);
    };

    const float* cxr = x_r0;
    const float* cxp = x_p0;
    const float* cxm = x_m0;
    float* bufs[2] = {xA, xB};
    for (int l = 0; l < 4; ++l) {
        int din = (l == 0) ? EMB_ : HID_;
        const float* Wl_ = (l == 0) ? Wl0 : WlL + (size_t)(l - 1) * 4 * HID_ * HID_;
        const float* Wr_ = (l == 0) ? Wr0 : WrL + (size_t)(l - 1) * 4 * HID_ * HID_;
        const float* bl_ = (l == 0) ? bl0 : blL + (size_t)(l - 1) * 4 * HID_;
        float* xb = bufs[l & 1];
        float* nxr = xb;
        float* nxp = xb + (size_t)NR_ * HID_;
        float* nxm = xb + (size_t)(NR_ + NP2_) * HID_;
        size_t wsz = (size_t)din * HID_;

        // lin_r parts (init new_x): reaction gets xr @ (Wr0+Wr1)
        k_addw<<<((int)wsz + 255) / 256, 256, 0, stream>>>(Wr_ + 0 * wsz, Wr_ + 1 * wsz, wc, (int)wsz);
        gemm(cxr, wc, nxr, NR_, HID_, din);
        gemm(cxp, Wr_ + 2 * wsz, nxp, NP2_, HID_, din);
        gemm(cxm, Wr_ + 3 * wsz, nxm, NM_, HID_, din);

        // lin_l parts: project source table, then mean-aggregate (+= mean + bias)
        gemm(cxp, Wl_ + 0 * wsz, proj, NP2_, HID_, din);
        k_aggregate<<<nd[0], 256, 0, stream>>>(offs[0], csr[0], proj, bl_ + 0 * HID_, nxr, nd[0]);
        gemm(cxm, Wl_ + 1 * wsz, proj, NM_, HID_, din);
        k_aggregate<<<nd[1], 256, 0, stream>>>(offs[1], csr[1], proj, bl_ + 1 * HID_, nxr, nd[1]);
        gemm(cxr, Wl_ + 2 * wsz, proj, NR_, HID_, din);
        k_aggregate<<<nd[2], 256, 0, stream>>>(offs[2], csr[2], proj, bl_ + 2 * HID_, nxp, nd[2]);
        gemm(cxr, Wl_ + 3 * wsz, proj, NR_, HID_, din);
        k_aggregate<<<nd[3], 256, 0, stream>>>(offs[3], csr[3], proj, bl_ + 3 * HID_, nxm, nd[3]);

        cxr = nxr; cxp = nxp; cxm = nxm;
    }

    k_final<<<NR_, 128, 0, stream>>>(cxr, Wre, bre, notes, types, Wn, bn, out);
}

// Round 2
// 1769.182 us; speedup vs baseline: 2.5548x; 2.5548x over previous
//
#include <hip/hip_runtime.h>
#include <math.h>
#include <stdint.h>

#define NR_ 16384
#define NP2_ 40000
#define NM_ 30000
#define NE_ 200000
#define EMB_ 1024
#define HID_ 256
#define OUTD_ 128

typedef __attribute__((ext_vector_type(8))) short bf16x8;
typedef __attribute__((ext_vector_type(4))) float f32x4;

__device__ __forceinline__ unsigned short f2bf(float f) {
    uint32_t u = __builtin_bit_cast(uint32_t, f);
    u = (u + 0x7FFFu + ((u >> 16) & 1u)) >> 16;
    return (unsigned short)u;
}

// ---------------- small utility kernels ----------------
__global__ void k_zero_i32(int* p, int n) {
    int i = blockIdx.x * 256 + threadIdx.x;
    if (i < n) p[i] = 0;
}
__global__ void k_copy_i32(int* d, const int* s, int n) {
    int i = blockIdx.x * 256 + threadIdx.x;
    if (i < n) d[i] = s[i];
}
__global__ void k_deg(const int* __restrict__ dst, int n, int* __restrict__ deg) {
    int i = blockIdx.x * 256 + threadIdx.x;
    if (i < n) atomicAdd(&deg[dst[i]], 1);
}
__global__ void k_scan(const int* __restrict__ deg, int* __restrict__ offs, int n) {
    __shared__ int buf[2][1024];
    __shared__ int carry;
    if (threadIdx.x == 0) carry = 0;
    __syncthreads();
    for (int base = 0; base < n; base += 1024) {
        int i = base + threadIdx.x;
        int v = (i < n) ? deg[i] : 0;
        int cur = 0;
        buf[0][threadIdx.x] = v;
        __syncthreads();
        for (int s = 1; s < 1024; s <<= 1) {
            int t = buf[cur][threadIdx.x];
            if (threadIdx.x >= (unsigned)s) t += buf[cur][threadIdx.x - s];
            buf[cur ^ 1][threadIdx.x] = t;
            cur ^= 1;
            __syncthreads();
        }
        int incl = buf[cur][threadIdx.x];
        if (i < n) offs[i] = carry + incl - v;
        __syncthreads();
        if (threadIdx.x == 1023) carry += incl;
        __syncthreads();
    }
    if (threadIdx.x == 0) offs[n] = carry;
}
__global__ void k_scatter(const int* __restrict__ src, const int* __restrict__ dst, int n,
                          int* __restrict__ cur, int* __restrict__ csr) {
    int i = blockIdx.x * 256 + threadIdx.x;
    if (i < n) {
        int d = dst[i];
        int p = atomicAdd(&cur[d], 1);
        csr[p] = src[i];
    }
}

// flat f32 -> bf16 (RNE), 4 elems/thread
__global__ void k_conv(const float* __restrict__ s, unsigned short* __restrict__ d, int n4) {
    int i = blockIdx.x * 256 + threadIdx.x;
    if (i < n4) {
        float4 v = ((const float4*)s)[i];
        ushort4 o;
        o.x = f2bf(v.x); o.y = f2bf(v.y); o.z = f2bf(v.z); o.w = f2bf(v.w);
        ((ushort4*)d)[i] = o;
    }
}

// batched weight transpose+convert: dst[n*K+k] = bf16(a[k*N+n] (+ b[k*N+n]))
struct WItem { const float* a; const float* b; unsigned short* dst; int k; int n; };
struct WBatch { WItem it[16]; };
__global__ void k_wconvT(WBatch wb) {
    WItem w = wb.it[blockIdx.y];
    int total = w.k * w.n;
    int kmask = w.k - 1;
    int shift = (w.k == 1024) ? 10 : 8;
    for (int idx = blockIdx.x * 256 + threadIdx.x; idx < total; idx += gridDim.x * 256) {
        int k = idx & kmask, n = idx >> shift;
        float v = w.a[(size_t)k * w.n + n];
        if (w.b) v += w.b[(size_t)k * w.n + n];
        w.dst[idx] = f2bf(v);
    }
}

// ---------------- bf16 MFMA GEMM: C[M,N] = A[M,K] @ Bt[N,K]^T (+bias) ----------------
// 128x128 tile, 4 waves, BK=64, global_load_lds staging with XOR chunk swizzle.
__global__ __launch_bounds__(256, 2) void k_gemm_bf16(
    const unsigned short* __restrict__ A, const unsigned short* __restrict__ Bt,
    float* __restrict__ C, const float* __restrict__ bias,
    int M, int N, int K)
{
    __shared__ __align__(16) unsigned short As[128 * 64];
    __shared__ __align__(16) unsigned short Bs[128 * 64];
    const int tid = threadIdx.x;
    const int lane = tid & 63;
    const int bm = blockIdx.x * 128;
    const int bn = blockIdx.y * 128;
    const int wave = tid >> 6;
    const int wr = (wave >> 1) * 64;
    const int wc = (wave & 1) * 64;
    const int frow = lane & 15;
    const int fkc = lane >> 4;
    f32x4 acc[4][4] = {};

    for (int k0 = 0; k0 < K; k0 += 64) {
        #pragma unroll
        for (int i = 0; i < 4; ++i) {
            int c = tid + i * 256;               // chunk 0..1023 (16B each)
            int row = c >> 3, kc = c & 7;
            int srck = k0 + ((kc ^ (row & 7)) << 3);  // pre-swizzled global source
            int ga = min(bm + row, M - 1);
            __builtin_amdgcn_global_load_lds(
                (const __attribute__((address_space(1))) unsigned int*)(A + (size_t)ga * K + srck),
                (__attribute__((address_space(3))) unsigned int*)(As + (size_t)c * 8), 16, 0, 0);
            __builtin_amdgcn_global_load_lds(
                (const __attribute__((address_space(1))) unsigned int*)(Bt + (size_t)(bn + row) * K + srck),
                (__attribute__((address_space(3))) unsigned int*)(Bs + (size_t)c * 8), 16, 0, 0);
        }
        __syncthreads();
        #pragma unroll
        for (int kk = 0; kk < 2; ++kk) {
            bf16x8 af[4], bfr[4];
            #pragma unroll
            for (int m = 0; m < 4; ++m) {
                int row = wr + m * 16 + frow;
                int kc = kk * 4 + fkc;
                af[m] = *(const bf16x8*)(As + (size_t)((row << 3) + (kc ^ (row & 7))) * 8);
            }
            #pragma unroll
            for (int n = 0; n < 4; ++n) {
                int row = wc + n * 16 + frow;
                int kc = kk * 4 + fkc;
                bfr[n] = *(const bf16x8*)(Bs + (size_t)((row << 3) + (kc ^ (row & 7))) * 8);
            }
            #pragma unroll
            for (int m = 0; m < 4; ++m)
                #pragma unroll
                for (int n = 0; n < 4; ++n)
                    acc[m][n] = __builtin_amdgcn_mfma_f32_16x16x32_bf16(af[m], bfr[n], acc[m][n], 0, 0, 0);
        }
        __syncthreads();
    }

    const int orow0 = (lane >> 4) << 2;
    #pragma unroll
    for (int m = 0; m < 4; ++m) {
        #pragma unroll
        for (int r = 0; r < 4; ++r) {
            int row = bm + wr + m * 16 + orow0 + r;
            if (row < M) {
                #pragma unroll
                for (int n = 0; n < 4; ++n) {
                    int col = bn + wc + n * 16 + frow;
                    float v = acc[m][n][r];
                    if (bias) v += bias[col];
                    C[(size_t)row * N + col] = v;
                }
            }
        }
    }
}

// ---------------- CSR mean-aggregate (+= mean + bias), HID=256 ----------------
__global__ __launch_bounds__(256) void k_aggregate(const int* __restrict__ offs,
                                                   const int* __restrict__ csr,
                                                   const float* __restrict__ proj,
                                                   const float* __restrict__ bias,
                                                   float* __restrict__ outx, int n_dst) {
    int node = blockIdx.x;
    int t = threadIdx.x;
    int beg = offs[node], end = offs[node + 1];
    __shared__ int idx[256];
    float sum = 0.f;
    for (int b = beg; b < end; b += 256) {
        int cnt = min(256, end - b);
        if (t < cnt) idx[t] = csr[b + t];
        __syncthreads();
        for (int e = 0; e < cnt; ++e) sum += proj[(size_t)idx[e] * HID_ + t];
        __syncthreads();
    }
    float c = (float)(end - beg);
    outx[(size_t)node * HID_ + t] += sum / fmaxf(c, 1.f) + bias[t];
}

// ---------------- cosine: one wave per row ----------------
__global__ __launch_bounds__(256) void k_cos(const float* __restrict__ ro,
                                             const float* __restrict__ pr,
                                             const int* __restrict__ types,
                                             float* __restrict__ out, int nr) {
    int row = blockIdx.x * 4 + (threadIdx.x >> 6);
    int lane = threadIdx.x & 63;
    if (row >= nr) return;
    int t = types[row];
    float2 r = ((const float2*)(ro + (size_t)row * OUTD_))[lane];
    float2 nn = ((const float2*)(pr + ((size_t)t * NR_ + row) * OUTD_))[lane];
    float num = r.x * nn.x + r.y * nn.y;
    float d1 = r.x * r.x + r.y * r.y;
    float d2 = nn.x * nn.x + nn.y * nn.y;
    #pragma unroll
    for (int s = 1; s < 64; s <<= 1) {
        num += __shfl_xor(num, s);
        d1 += __shfl_xor(d1, s);
        d2 += __shfl_xor(d2, s);
    }
    if (lane == 0) out[row] = (num / fmaxf(sqrtf(d1) * sqrtf(d2), 1e-8f) + 1.f) * 0.5f;
}

extern "C" void kernel_launch(void* const* d_in, const int* in_sizes, int n_in,
                              void* d_out, int out_size, void* d_ws, size_t ws_size,
                              hipStream_t stream) {
    const float* x_r0 = (const float*)d_in[0];
    const float* x_p0 = (const float*)d_in[1];
    const float* x_m0 = (const float*)d_in[2];
    const int* es[4][2] = {
        {(const int*)d_in[3], (const int*)d_in[4]},   // p2r
        {(const int*)d_in[5], (const int*)d_in[6]},   // m2r
        {(const int*)d_in[7], (const int*)d_in[8]},   // r2p
        {(const int*)d_in[9], (const int*)d_in[10]},  // r2m
    };
    const float* notes = (const float*)d_in[11];
    const int* types = (const int*)d_in[12];
    const float* Wl0 = (const float*)d_in[13];
    const float* Wr0 = (const float*)d_in[14];
    const float* bl0 = (const float*)d_in[15];
    const float* WlL = (const float*)d_in[16];
    const float* WrL = (const float*)d_in[17];
    const float* blL = (const float*)d_in[18];
    const float* Wre = (const float*)d_in[19];
    const float* bre = (const float*)d_in[20];
    const float* Wn  = (const float*)d_in[21];
    const float* bn  = (const float*)d_in[22];
    float* out = (float*)d_out;

    // ---- workspace carve ----
    uintptr_t base = (uintptr_t)d_ws;
    auto alloc = [&](size_t bytes) -> void* {
        uintptr_t p = (base + 255) & ~(uintptr_t)255;
        base = p + bytes;
        return (void*)p;
    };
    const size_t NX = (size_t)(NR_ + NP2_ + NM_) * HID_;
    float* xF = (float*)alloc(NX * 4);                                   // f32 new_x (r|p|m)
    unsigned short* xbf = (unsigned short*)alloc((size_t)NP2_ * EMB_ * 2); // bf16 table scratch (max 40000x1024)
    unsigned short* notesbf = (unsigned short*)alloc((size_t)NR_ * EMB_ * 2);
    float* projP  = (float*)alloc((size_t)NP2_ * HID_ * 4);
    float* projM  = (float*)alloc((size_t)NM_ * HID_ * 4);
    float* projR  = (float*)alloc((size_t)NR_ * HID_ * 4);
    float* projR2 = (float*)alloc((size_t)NR_ * HID_ * 4);
    float* finbuf = (float*)alloc((size_t)4 * NR_ * OUTD_ * 4);          // ro | pr[3]
    unsigned short* wbf = (unsigned short*)alloc((size_t)4000000 * 2);
    int nd[4] = {NR_, NR_, NP2_, NM_};
    int *offs[4], *curp[4], *csr[4];
    for (int t = 0; t < 4; ++t) {
        offs[t] = (int*)alloc(((size_t)nd[t] + 1) * 4);
        curp[t] = (int*)alloc((size_t)nd[t] * 4);
        csr[t]  = (int*)alloc((size_t)NE_ * 4);
    }

    // ---- weight transpose+convert (bf16 [N][K]), batched: 32 items ----
    unsigned short* wT_l0[7]; unsigned short* wT_l[3][7]; unsigned short* wT_re; unsigned short* wT_n[3];
    {
        WBatch b0{}, b1{};
        WItem* items[2] = {b0.it, b1.it};
        int cnt = 0;
        size_t woff = 0;
        auto add = [&](const float* a, const float* bb, int K, int N) -> unsigned short* {
            unsigned short* dst = wbf + woff;
            woff += (size_t)K * N;
            items[cnt >> 4][cnt & 15] = WItem{a, bb, dst, K, N};
            ++cnt;
            return dst;
        };
        const size_t w0 = (size_t)EMB_ * HID_;   // 262144
        const size_t wl = (size_t)HID_ * HID_;   // 65536
        wT_l0[0] = add(Wr0 + 0 * w0, Wr0 + 1 * w0, EMB_, HID_);   // Wr combined (reaction)
        wT_l0[1] = add(Wr0 + 2 * w0, nullptr, EMB_, HID_);
        wT_l0[2] = add(Wr0 + 3 * w0, nullptr, EMB_, HID_);
        for (int t = 0; t < 4; ++t) wT_l0[3 + t] = add(Wl0 + t * w0, nullptr, EMB_, HID_);
        for (int l = 0; l < 3; ++l) {
            const float* Wr_ = WrL + (size_t)l * 4 * wl;
            const float* Wl_ = WlL + (size_t)l * 4 * wl;
            wT_l[l][0] = add(Wr_ + 0 * wl, Wr_ + 1 * wl, HID_, HID_);
            wT_l[l][1] = add(Wr_ + 2 * wl, nullptr, HID_, HID_);
            wT_l[l][2] = add(Wr_ + 3 * wl, nullptr, HID_, HID_);
            for (int t = 0; t < 4; ++t) wT_l[l][3 + t] = add(Wl_ + t * wl, nullptr, HID_, HID_);
        }
        wT_re = add(Wre, nullptr, HID_, OUTD_);
        for (int t = 0; t < 3; ++t) wT_n[t] = add(Wn + (size_t)t * EMB_ * OUTD_, nullptr, EMB_, OUTD_);
        k_wconvT<<<dim3(256, 16), 256, 0, stream>>>(b0);
        k_wconvT<<<dim3(256, cnt - 16), 256, 0, stream>>>(b1);
    }

    // ---- CSR build ----
    for (int t = 0; t < 4; ++t) {
        int n = nd[t];
        k_zero_i32<<<(n + 255) / 256, 256, 0, stream>>>(curp[t], n);
        k_deg<<<(NE_ + 255) / 256, 256, 0, stream>>>(es[t][1], NE_, curp[t]);
        k_scan<<<1, 1024, 0, stream>>>(curp[t], offs[t], n);
        k_copy_i32<<<(n + 255) / 256, 256, 0, stream>>>(curp[t], offs[t], n);
        k_scatter<<<(NE_ + 255) / 256, 256, 0, stream>>>(es[t][0], es[t][1], NE_, curp[t], csr[t]);
    }

    // ---- notes -> bf16 ----
    k_conv<<<(NR_ * EMB_ / 4 + 255) / 256, 256, 0, stream>>>(notes, notesbf, NR_ * EMB_ / 4);

    auto gemm = [&](const unsigned short* A, const unsigned short* Bt, float* C,
                    const float* bias, int M, int N, int K) {
        dim3 g((M + 127) / 128, N / 128);
        k_gemm_bf16<<<g, 256, 0, stream>>>(A, Bt, C, bias, M, N, K);
    };
    auto conv = [&](const float* s, unsigned short* d, size_t n) {
        k_conv<<<((int)(n / 4) + 255) / 256, 256, 0, stream>>>(s, d, (int)(n / 4));
    };

    float* nxr = xF;
    float* nxp = xF + (size_t)NR_ * HID_;
    float* nxm = xF + (size_t)(NR_ + NP2_) * HID_;

    // ---- layer 0 (K = EMB) : convert one source table at a time ----
    conv(x_r0, xbf, (size_t)NR_ * EMB_);
    gemm(xbf, wT_l0[0], nxr,    nullptr, NR_, HID_, EMB_);
    gemm(xbf, wT_l0[5], projR,  nullptr, NR_, HID_, EMB_);   // Wl[2]: r2p source proj
    gemm(xbf, wT_l0[6], projR2, nullptr, NR_, HID_, EMB_);   // Wl[3]: r2m source proj
    conv(x_p0, xbf, (size_t)NP2_ * EMB_);
    gemm(xbf, wT_l0[1], nxp,   nullptr, NP2_, HID_, EMB_);
    gemm(xbf, wT_l0[3], projP, nullptr, NP2_, HID_, EMB_);   // Wl[0]: p2r
    conv(x_m0, xbf, (size_t)NM_ * EMB_);
    gemm(xbf, wT_l0[2], nxm,   nullptr, NM_, HID_, EMB_);
    gemm(xbf, wT_l0[4], projM, nullptr, NM_, HID_, EMB_);    // Wl[1]: m2r
    k_aggregate<<<nd[0], 256, 0, stream>>>(offs[0], csr[0], projP,  bl0 + 0 * HID_, nxr, nd[0]);
    k_aggregate<<<nd[1], 256, 0, stream>>>(offs[1], csr[1], projM,  bl0 + 1 * HID_, nxr, nd[1]);
    k_aggregate<<<nd[2], 256, 0, stream>>>(offs[2], csr[2], projR,  bl0 + 2 * HID_, nxp, nd[2]);
    k_aggregate<<<nd[3], 256, 0, stream>>>(offs[3], csr[3], projR2, bl0 + 3 * HID_, nxm, nd[3]);

    // ---- layers 1..3 (K = HID) ----
    unsigned short* xbr = xbf;
    unsigned short* xbp = xbf + (size_t)NR_ * HID_;
    unsigned short* xbm = xbf + (size_t)(NR_ + NP2_) * HID_;
    for (int l = 0; l < 3; ++l) {
        const float* bl_ = blL + (size_t)l * 4 * HID_;
        conv(xF, xbf, NX);   // all three tables
        gemm(xbr, wT_l[l][0], nxr,    nullptr, NR_,  HID_, HID_);
        gemm(xbr, wT_l[l][5], projR,  nullptr, NR_,  HID_, HID_);
        gemm(xbr, wT_l[l][6], projR2, nullptr, NR_,  HID_, HID_);
        gemm(xbp, wT_l[l][1], nxp,    nullptr, NP2_, HID_, HID_);
        gemm(xbp, wT_l[l][3], projP,  nullptr, NP2_, HID_, HID_);
        gemm(xbm, wT_l[l][2], nxm,    nullptr, NM_,  HID_, HID_);
        gemm(xbm, wT_l[l][4], projM,  nullptr, NM_,  HID_, HID_);
        k_aggregate<<<nd[0], 256, 0, stream>>>(offs[0], csr[0], projP,  bl_ + 0 * HID_, nxr, nd[0]);
        k_aggregate<<<nd[1], 256, 0, stream>>>(offs[1], csr[1], projM,  bl_ + 1 * HID_, nxr, nd[1]);
        k_aggregate<<<nd[2], 256, 0, stream>>>(offs[2], csr[2], projR,  bl_ + 2 * HID_, nxp, nd[2]);
        k_aggregate<<<nd[3], 256, 0, stream>>>(offs[3], csr[3], projR2, bl_ + 3 * HID_, nxm, nd[3]);
    }

    // ---- final: reaction proj + 3 node projs + cosine ----
    conv(nxr, xbr, (size_t)NR_ * HID_);
    float* ro = finbuf;
    float* pr = finbuf + (size_t)NR_ * OUTD_;
    gemm(xbr, wT_re, ro, bre, NR_, OUTD_, HID_);
    for (int t = 0; t < 3; ++t)
        gemm(notesbf, wT_n[t], pr + (size_t)t * NR_ * OUTD_, bn + t * OUTD_, NR_, OUTD_, EMB_);
    k_cos<<<NR_ / 4, 256, 0, stream>>>(ro, pr, types, out, NR_);
}

// Round 3
// 1183.619 us; speedup vs baseline: 3.8187x; 1.4947x over previous
//
#include <hip/hip_runtime.h>
#include <math.h>
#include <stdint.h>

#define NR_ 16384
#define NP2_ 40000
#define NM_ 30000
#define NE_ 200000
#define EMB_ 1024
#define HID_ 256
#define OUTD_ 128

typedef __attribute__((ext_vector_type(8))) short bf16x8;
typedef __attribute__((ext_vector_type(4))) float f32x4;

__device__ __forceinline__ unsigned short f2bf(float f) {
    uint32_t u = __builtin_bit_cast(uint32_t, f);
    u = (u + 0x7FFFu + ((u >> 16) & 1u)) >> 16;
    return (unsigned short)u;
}
__device__ __forceinline__ float bf2f(unsigned short u) {
    uint32_t v = ((uint32_t)u) << 16;
    return __builtin_bit_cast(float, v);
}

// ---------------- batched CSR build ----------------
struct Csr4 {
    const int* src[4]; const int* dst[4];
    int* offs[4]; int* cur[4]; int* csr[4];
    int n[4];
};
__global__ void k_zero4(Csr4 c) {
    int y = blockIdx.y;
    int i = blockIdx.x * 256 + threadIdx.x;
    if (i < c.n[y]) c.cur[y][i] = 0;
}
__global__ void k_deg4(Csr4 c) {
    int y = blockIdx.y;
    int i = blockIdx.x * 256 + threadIdx.x;
    if (i < NE_) atomicAdd(&c.cur[y][c.dst[y][i]], 1);
}
__global__ void k_scan4(Csr4 c) {
    int y = blockIdx.x;
    const int* deg = c.cur[y];
    int* offs = c.offs[y];
    int n = c.n[y];
    __shared__ int buf[2][1024];
    __shared__ int carry;
    if (threadIdx.x == 0) carry = 0;
    __syncthreads();
    for (int base = 0; base < n; base += 1024) {
        int i = base + threadIdx.x;
        int v = (i < n) ? deg[i] : 0;
        int cur = 0;
        buf[0][threadIdx.x] = v;
        __syncthreads();
        for (int s = 1; s < 1024; s <<= 1) {
            int t = buf[cur][threadIdx.x];
            if (threadIdx.x >= (unsigned)s) t += buf[cur][threadIdx.x - s];
            buf[cur ^ 1][threadIdx.x] = t;
            cur ^= 1;
            __syncthreads();
        }
        int incl = buf[cur][threadIdx.x];
        if (i < n) offs[i] = carry + incl - v;
        __syncthreads();
        if (threadIdx.x == 1023) carry += incl;
        __syncthreads();
    }
    if (threadIdx.x == 0) offs[n] = carry;
}
__global__ void k_copy4(Csr4 c) {
    int y = blockIdx.y;
    int i = blockIdx.x * 256 + threadIdx.x;
    if (i < c.n[y]) c.cur[y][i] = c.offs[y][i];
}
__global__ void k_scatter4(Csr4 c) {
    int y = blockIdx.y;
    int i = blockIdx.x * 256 + threadIdx.x;
    if (i < NE_) {
        int d = c.dst[y][i];
        int p = atomicAdd(&c.cur[y][d], 1);
        c.csr[y][p] = c.src[y][i];
    }
}

// ---------------- batched f32 -> bf16 conversion ----------------
struct Conv4 { const float* s[4]; unsigned short* d[4]; int n4[4]; };
__global__ void k_conv4(Conv4 cv) {
    int y = blockIdx.y;
    const float* s = cv.s[y];
    unsigned short* d = cv.d[y];
    int n4 = cv.n4[y];
    for (int i = blockIdx.x * 256 + threadIdx.x; i < n4; i += gridDim.x * 256) {
        float4 v = ((const float4*)s)[i];
        ushort4 o;
        o.x = f2bf(v.x); o.y = f2bf(v.y); o.z = f2bf(v.z); o.w = f2bf(v.w);
        ((ushort4*)d)[i] = o;
    }
}

// batched weight transpose+convert: dst[n*K+k] = bf16(a[k*N+n] (+ b[k*N+n]))
struct WItem { const float* a; const float* b; unsigned short* dst; int k; int n; };
struct WBatch { WItem it[16]; };
__global__ void k_wconvT(WBatch wb) {
    WItem w = wb.it[blockIdx.y];
    int total = w.k * w.n;
    int kmask = w.k - 1;
    int shift = (w.k == 1024) ? 10 : 8;
    for (int idx = blockIdx.x * 256 + threadIdx.x; idx < total; idx += gridDim.x * 256) {
        int k = idx & kmask, n = idx >> shift;
        float v = w.a[(size_t)k * w.n + n];
        if (w.b) v += w.b[(size_t)k * w.n + n];
        w.dst[idx] = f2bf(v);
    }
}

// ---------------- bf16 MFMA GEMM: C[M, gridDim.y*128] = A[M,K](lda) @ Bt[N,K]^T ----------------
// 128x128 tile, 4 waves, BK=64, global_load_lds staging with XOR chunk swizzle.
// OBF: write bf16 output, else f32 (+bias if non-null).
template <bool OBF>
__global__ __launch_bounds__(256, 2) void k_gemm(
    const unsigned short* __restrict__ A, int lda,
    const unsigned short* __restrict__ Bt,
    void* __restrict__ Cv, int ldc, const float* __restrict__ bias,
    int M, int K)
{
    __shared__ __align__(16) unsigned short As[128 * 64];
    __shared__ __align__(16) unsigned short Bs[128 * 64];
    const int tid = threadIdx.x;
    const int lane = tid & 63;
    const int bm = blockIdx.x * 128;
    const int bn = blockIdx.y * 128;
    const int wave = tid >> 6;
    const int wr = (wave >> 1) * 64;
    const int wc = (wave & 1) * 64;
    const int frow = lane & 15;
    const int fkc = lane >> 4;
    f32x4 acc[4][4] = {};

    for (int k0 = 0; k0 < K; k0 += 64) {
        #pragma unroll
        for (int i = 0; i < 4; ++i) {
            int c = tid + i * 256;               // chunk 0..1023 (16B each)
            int row = c >> 3, kc = c & 7;
            int srck = k0 + ((kc ^ (row & 7)) << 3);  // pre-swizzled global source
            int ga = min(bm + row, M - 1);
            __builtin_amdgcn_global_load_lds(
                (const __attribute__((address_space(1))) unsigned int*)(A + (size_t)ga * lda + srck),
                (__attribute__((address_space(3))) unsigned int*)(As + (size_t)c * 8), 16, 0, 0);
            __builtin_amdgcn_global_load_lds(
                (const __attribute__((address_space(1))) unsigned int*)(Bt + (size_t)(bn + row) * K + srck),
                (__attribute__((address_space(3))) unsigned int*)(Bs + (size_t)c * 8), 16, 0, 0);
        }
        __syncthreads();
        #pragma unroll
        for (int kk = 0; kk < 2; ++kk) {
            bf16x8 af[4], bfr[4];
            #pragma unroll
            for (int m = 0; m < 4; ++m) {
                int row = wr + m * 16 + frow;
                int kc = kk * 4 + fkc;
                af[m] = *(const bf16x8*)(As + (size_t)((row << 3) + (kc ^ (row & 7))) * 8);
            }
            #pragma unroll
            for (int n = 0; n < 4; ++n) {
                int row = wc + n * 16 + frow;
                int kc = kk * 4 + fkc;
                bfr[n] = *(const bf16x8*)(Bs + (size_t)((row << 3) + (kc ^ (row & 7))) * 8);
            }
            #pragma unroll
            for (int m = 0; m < 4; ++m)
                #pragma unroll
                for (int n = 0; n < 4; ++n)
                    acc[m][n] = __builtin_amdgcn_mfma_f32_16x16x32_bf16(af[m], bfr[n], acc[m][n], 0, 0, 0);
        }
        __syncthreads();
    }

    const int orow0 = (lane >> 4) << 2;
    #pragma unroll
    for (int m = 0; m < 4; ++m) {
        #pragma unroll
        for (int r = 0; r < 4; ++r) {
            int row = bm + wr + m * 16 + orow0 + r;
            if (row < M) {
                #pragma unroll
                for (int n = 0; n < 4; ++n) {
                    int col = bn + wc + n * 16 + frow;
                    float v = acc[m][n][r];
                    if (bias) v += bias[col];
                    if constexpr (OBF)
                        ((unsigned short*)Cv)[(size_t)row * ldc + col] = f2bf(v);
                    else
                        ((float*)Cv)[(size_t)row * ldc + col] = v;
                }
            }
        }
    }
}

// ---------------- CSR mean-aggregate (bf16 RMW: outx += mean + bias) ----------------
__global__ __launch_bounds__(256) void k_agg(const int* __restrict__ offs,
                                             const int* __restrict__ csr,
                                             const unsigned short* __restrict__ proj, int ldp,
                                             const float* __restrict__ bias,
                                             unsigned short* __restrict__ outx, int ldo) {
    int node = blockIdx.x;
    int t = threadIdx.x;
    int beg = offs[node], end = offs[node + 1];
    __shared__ int idx[256];
    float sum = 0.f;
    for (int b = beg; b < end; b += 256) {
        int cnt = min(256, end - b);
        if (t < cnt) idx[t] = csr[b + t];
        __syncthreads();
        for (int e = 0; e < cnt; ++e) sum += bf2f(proj[(size_t)idx[e] * ldp + t]);
        __syncthreads();
    }
    float c = (float)(end - beg);
    size_t o = (size_t)node * ldo + t;
    float v = bf2f(outx[o]) + sum / fmaxf(c, 1.f) + bias[t];
    outx[o] = f2bf(v);
}

// dual-source aggregate (reaction dst: p2r + m2r in one pass)
__global__ __launch_bounds__(256) void k_agg2(const int* __restrict__ offsA,
                                              const int* __restrict__ csrA,
                                              const unsigned short* __restrict__ projA, int ldpA,
                                              const float* __restrict__ biasA,
                                              const int* __restrict__ offsB,
                                              const int* __restrict__ csrB,
                                              const unsigned short* __restrict__ projB, int ldpB,
                                              const float* __restrict__ biasB,
                                              unsigned short* __restrict__ outx, int ldo) {
    int node = blockIdx.x;
    int t = threadIdx.x;
    __shared__ int idx[256];
    float sumA = 0.f, sumB = 0.f;
    int begA = offsA[node], endA = offsA[node + 1];
    for (int b = begA; b < endA; b += 256) {
        int cnt = min(256, endA - b);
        if (t < cnt) idx[t] = csrA[b + t];
        __syncthreads();
        for (int e = 0; e < cnt; ++e) sumA += bf2f(projA[(size_t)idx[e] * ldpA + t]);
        __syncthreads();
    }
    int begB = offsB[node], endB = offsB[node + 1];
    for (int b = begB; b < endB; b += 256) {
        int cnt = min(256, endB - b);
        if (t < cnt) idx[t] = csrB[b + t];
        __syncthreads();
        for (int e = 0; e < cnt; ++e) sumB += bf2f(projB[(size_t)idx[e] * ldpB + t]);
        __syncthreads();
    }
    float cA = (float)(endA - begA), cB = (float)(endB - begB);
    size_t o = (size_t)node * ldo + t;
    float v = bf2f(outx[o]) + sumA / fmaxf(cA, 1.f) + biasA[t] + sumB / fmaxf(cB, 1.f) + biasB[t];
    outx[o] = f2bf(v);
}

// ---------------- cosine: one wave per row ----------------
__global__ __launch_bounds__(256) void k_cos(const float* __restrict__ ro,
                                             const float* __restrict__ pr,
                                             const int* __restrict__ types,
                                             float* __restrict__ out, int nr) {
    int row = blockIdx.x * 4 + (threadIdx.x >> 6);
    int lane = threadIdx.x & 63;
    if (row >= nr) return;
    int t = types[row];
    float2 r = ((const float2*)(ro + (size_t)row * OUTD_))[lane];
    float2 nn = ((const float2*)(pr + (size_t)row * 384 + t * OUTD_))[lane];
    float num = r.x * nn.x + r.y * nn.y;
    float d1 = r.x * r.x + r.y * r.y;
    float d2 = nn.x * nn.x + nn.y * nn.y;
    #pragma unroll
    for (int s = 1; s < 64; s <<= 1) {
        num += __shfl_xor(num, s);
        d1 += __shfl_xor(d1, s);
        d2 += __shfl_xor(d2, s);
    }
    if (lane == 0) out[row] = (num / fmaxf(sqrtf(d1) * sqrtf(d2), 1e-8f) + 1.f) * 0.5f;
}

extern "C" void kernel_launch(void* const* d_in, const int* in_sizes, int n_in,
                              void* d_out, int out_size, void* d_ws, size_t ws_size,
                              hipStream_t stream) {
    const float* x_r0 = (const float*)d_in[0];
    const float* x_p0 = (const float*)d_in[1];
    const float* x_m0 = (const float*)d_in[2];
    const int* e_src[4] = {(const int*)d_in[3], (const int*)d_in[5], (const int*)d_in[7], (const int*)d_in[9]};
    const int* e_dst[4] = {(const int*)d_in[4], (const int*)d_in[6], (const int*)d_in[8], (const int*)d_in[10]};
    const float* notes = (const float*)d_in[11];
    const int* types = (const int*)d_in[12];
    const float* Wl0 = (const float*)d_in[13];
    const float* Wr0 = (const float*)d_in[14];
    const float* bl0 = (const float*)d_in[15];
    const float* WlL = (const float*)d_in[16];
    const float* WrL = (const float*)d_in[17];
    const float* blL = (const float*)d_in[18];
    const float* Wre = (const float*)d_in[19];
    const float* bre = (const float*)d_in[20];
    const float* Wn  = (const float*)d_in[21];
    const float* bn  = (const float*)d_in[22];
    float* out = (float*)d_out;

    // ---- workspace carve ----
    uintptr_t base = (uintptr_t)d_ws;
    auto alloc = [&](size_t bytes) -> void* {
        uintptr_t p = (base + 255) & ~(uintptr_t)255;
        base = p + bytes;
        return (void*)p;
    };
    // x buffers: R [NR][768], P [NP2][512], M [NM][512], double-buffered, bf16
    unsigned short* Rb[2] = {(unsigned short*)alloc((size_t)NR_ * 768 * 2),
                             (unsigned short*)alloc((size_t)NR_ * 768 * 2)};
    unsigned short* Pb[2] = {(unsigned short*)alloc((size_t)NP2_ * 512 * 2),
                             (unsigned short*)alloc((size_t)NP2_ * 512 * 2)};
    unsigned short* Mb[2] = {(unsigned short*)alloc((size_t)NM_ * 512 * 2),
                             (unsigned short*)alloc((size_t)NM_ * 512 * 2)};
    unsigned short* xr0bf = (unsigned short*)alloc((size_t)NR_ * EMB_ * 2);
    unsigned short* xp0bf = (unsigned short*)alloc((size_t)NP2_ * EMB_ * 2);
    unsigned short* xm0bf = (unsigned short*)alloc((size_t)NM_ * EMB_ * 2);
    unsigned short* notesbf = (unsigned short*)alloc((size_t)NR_ * EMB_ * 2);
    float* ro = (float*)alloc((size_t)NR_ * OUTD_ * 4);
    float* pr = (float*)alloc((size_t)NR_ * 384 * 4);
    unsigned short* wbf = (unsigned short*)alloc((size_t)4000000 * 2);
    int nd[4] = {NR_, NR_, NP2_, NM_};
    Csr4 cs{};
    for (int t = 0; t < 4; ++t) {
        cs.src[t] = e_src[t]; cs.dst[t] = e_dst[t]; cs.n[t] = nd[t];
        cs.offs[t] = (int*)alloc(((size_t)nd[t] + 1) * 4);
        cs.cur[t]  = (int*)alloc((size_t)nd[t] * 4);
        cs.csr[t]  = (int*)alloc((size_t)NE_ * 4);
    }

    // ---- weight transpose+convert: concatenated B blocks, bf16 [N][K] ----
    // per layer: Bx_r = [WrC | Wl2 | Wl3] (768 x K), Bx_p = [Wr2 | Wl0] (512 x K), Bx_m = [Wr3 | Wl1]
    unsigned short *BR[4], *BP[4], *BM[4], *Bre, *Bn;
    {
        WBatch b0{}, b1{};
        WItem* items[2] = {b0.it, b1.it};
        int cnt = 0;
        size_t woff = 0;
        auto add = [&](const float* a, const float* bb, int K, int N) -> unsigned short* {
            unsigned short* dst = wbf + woff;
            woff += (size_t)K * N;
            items[cnt >> 4][cnt & 15] = WItem{a, bb, dst, K, N};
            ++cnt;
            return dst;
        };
        const size_t w0 = (size_t)EMB_ * HID_;
        const size_t wl = (size_t)HID_ * HID_;
        for (int l = 0; l < 4; ++l) {
            int K = (l == 0) ? EMB_ : HID_;
            const float* Wr_ = (l == 0) ? Wr0 : WrL + (size_t)(l - 1) * 4 * wl;
            const float* Wl_ = (l == 0) ? Wl0 : WlL + (size_t)(l - 1) * 4 * wl;
            size_t ws_ = (l == 0) ? w0 : wl;
            BR[l] = add(Wr_ + 0 * ws_, Wr_ + 1 * ws_, K, HID_);  // WrC
            add(Wl_ + 2 * ws_, nullptr, K, HID_);                 // Wl2 (r2p proj)
            add(Wl_ + 3 * ws_, nullptr, K, HID_);                 // Wl3 (r2m proj)
            BP[l] = add(Wr_ + 2 * ws_, nullptr, K, HID_);         // Wr2
            add(Wl_ + 0 * ws_, nullptr, K, HID_);                 // Wl0 (p2r proj)
            BM[l] = add(Wr_ + 3 * ws_, nullptr, K, HID_);         // Wr3
            add(Wl_ + 1 * ws_, nullptr, K, HID_);                 // Wl1 (m2r proj)
        }
        Bre = add(Wre, nullptr, HID_, OUTD_);
        Bn = add(Wn + 0 * (size_t)EMB_ * OUTD_, nullptr, EMB_, OUTD_);
        add(Wn + 1 * (size_t)EMB_ * OUTD_, nullptr, EMB_, OUTD_);
        add(Wn + 2 * (size_t)EMB_ * OUTD_, nullptr, EMB_, OUTD_);
        k_wconvT<<<dim3(128, 16), 256, 0, stream>>>(b0);
        k_wconvT<<<dim3(128, cnt - 16), 256, 0, stream>>>(b1);
    }

    // ---- CSR build (batched over the 4 edge types) ----
    k_zero4<<<dim3((NP2_ + 255) / 256, 4), 256, 0, stream>>>(cs);
    k_deg4<<<dim3((NE_ + 255) / 256, 4), 256, 0, stream>>>(cs);
    k_scan4<<<4, 1024, 0, stream>>>(cs);
    k_copy4<<<dim3((NP2_ + 255) / 256, 4), 256, 0, stream>>>(cs);
    k_scatter4<<<dim3((NE_ + 255) / 256, 4), 256, 0, stream>>>(cs);

    // ---- input tables + notes -> bf16 (batched) ----
    {
        Conv4 cv{};
        cv.s[0] = x_r0; cv.d[0] = xr0bf; cv.n4[0] = NR_ * EMB_ / 4;
        cv.s[1] = x_p0; cv.d[1] = xp0bf; cv.n4[1] = NP2_ * EMB_ / 4;
        cv.s[2] = x_m0; cv.d[2] = xm0bf; cv.n4[2] = NM_ * EMB_ / 4;
        cv.s[3] = notes; cv.d[3] = notesbf; cv.n4[3] = NR_ * EMB_ / 4;
        k_conv4<<<dim3(1024, 4), 256, 0, stream>>>(cv);
    }

    auto gemm_bf = [&](const unsigned short* A, int lda, const unsigned short* Bt,
                       unsigned short* C, int ldc, int M, int N, int K) {
        k_gemm<true><<<dim3((M + 127) / 128, N / 128), 256, 0, stream>>>(A, lda, Bt, C, ldc, nullptr, M, K);
    };

    for (int l = 0; l < 4; ++l) {
        int K = (l == 0) ? EMB_ : HID_;
        const unsigned short* axr = (l == 0) ? xr0bf : Rb[(l - 1) & 1];
        const unsigned short* axp = (l == 0) ? xp0bf : Pb[(l - 1) & 1];
        const unsigned short* axm = (l == 0) ? xm0bf : Mb[(l - 1) & 1];
        int lar = (l == 0) ? EMB_ : 768;
        int lapm = (l == 0) ? EMB_ : 512;
        unsigned short* R = Rb[l & 1];
        unsigned short* P = Pb[l & 1];
        unsigned short* M = Mb[l & 1];
        const float* bl_ = (l == 0) ? bl0 : blL + (size_t)(l - 1) * 4 * HID_;

        gemm_bf(axr, lar, BR[l], R, 768, NR_, 768, K);
        gemm_bf(axp, lapm, BP[l], P, 512, NP2_, 512, K);
        gemm_bf(axm, lapm, BM[l], M, 512, NM_, 512, K);

        // reaction <- mean(projP) + mean(projM); protein <- mean(projR); molecule <- mean(projR2)
        k_agg2<<<NR_, 256, 0, stream>>>(cs.offs[0], cs.csr[0], P + 256, 512, bl_ + 0 * HID_,
                                        cs.offs[1], cs.csr[1], M + 256, 512, bl_ + 1 * HID_,
                                        R, 768);
        k_agg<<<NP2_, 256, 0, stream>>>(cs.offs[2], cs.csr[2], R + 256, 768, bl_ + 2 * HID_, P, 512);
        k_agg<<<NM_, 256, 0, stream>>>(cs.offs[3], cs.csr[3], R + 512, 768, bl_ + 3 * HID_, M, 512);
    }

    // ---- final: reaction proj (f32) + 3 node projs (f32, concatenated) + cosine ----
    k_gemm<false><<<dim3((NR_ + 127) / 128, 1), 256, 0, stream>>>(
        Rb[1], 768, Bre, ro, OUTD_, bre, NR_, HID_);
    k_gemm<false><<<dim3((NR_ + 127) / 128, 3), 256, 0, stream>>>(
        notesbf, EMB_, Bn, pr, 384, bn, NR_, EMB_);
    k_cos<<<NR_ / 4, 256, 0, stream>>>(ro, pr, types, out, NR_);
}

// Round 4
// 1050.377 us; speedup vs baseline: 4.3031x; 1.1269x over previous
//
#include <hip/hip_runtime.h>
#include <math.h>
#include <stdint.h>

#define NR_ 16384
#define NP2_ 40000
#define NM_ 30000
#define NE_ 200000
#define EMB_ 1024
#define HID_ 256
#define OUTD_ 128

typedef __attribute__((ext_vector_type(8))) short bf16x8;
typedef __attribute__((ext_vector_type(4))) float f32x4;

__device__ __forceinline__ unsigned short f2bf(float f) {
    uint32_t u = __builtin_bit_cast(uint32_t, f);
    u = (u + 0x7FFFu + ((u >> 16) & 1u)) >> 16;
    return (unsigned short)u;
}
__device__ __forceinline__ float bf2f(unsigned short u) {
    uint32_t v = ((uint32_t)u) << 16;
    return __builtin_bit_cast(float, v);
}

// ---------------- batched CSR build ----------------
struct Csr4 {
    const int* src[4]; const int* dst[4];
    int* offs[4]; int* cur[4]; int* csr[4];
    int n[4];
};
__global__ void k_zero4(Csr4 c) {
    int y = blockIdx.y;
    int i = blockIdx.x * 256 + threadIdx.x;
    if (i < c.n[y]) c.cur[y][i] = 0;
}
__global__ void k_deg4(Csr4 c) {
    int y = blockIdx.y;
    int i = blockIdx.x * 256 + threadIdx.x;
    if (i < NE_) atomicAdd(&c.cur[y][c.dst[y][i]], 1);
}
// two-level scan: A = per-1024-chunk block scan, B = chunk-sum scan, C = add base + init cur
__global__ void k_scanA(Csr4 c, int* __restrict__ csum) {
    int y = blockIdx.y;
    int n = c.n[y];
    int ch = blockIdx.x;
    int nch = (n + 1023) >> 10;
    if (ch >= nch) return;
    const int* deg = c.cur[y];
    int* offs = c.offs[y];
    __shared__ int ts[256];
    int base = ch << 10;
    int t = threadIdx.x;
    int v[4];
    int s = 0;
    #pragma unroll
    for (int k = 0; k < 4; ++k) {
        int i = base + t * 4 + k;
        v[k] = (i < n) ? deg[i] : 0;
        s += v[k];
    }
    ts[t] = s;
    __syncthreads();
    for (int st = 1; st < 256; st <<= 1) {
        int x = ts[t];
        int xo = (t >= st) ? ts[t - st] : 0;
        __syncthreads();
        ts[t] = x + xo;
        __syncthreads();
    }
    int run = (t > 0) ? ts[t - 1] : 0;
    #pragma unroll
    for (int k = 0; k < 4; ++k) {
        int i = base + t * 4 + k;
        if (i < n) offs[i] = run;
        run += v[k];
    }
    if (t == 255) csum[y * 40 + ch] = ts[255];
}
__global__ void k_scanB(Csr4 c, int* __restrict__ csum) {
    int y = threadIdx.x;
    if (y < 4) {
        int n = c.n[y];
        int nch = (n + 1023) >> 10;
        int acc = 0;
        for (int i = 0; i < nch; ++i) {
            int v = csum[y * 40 + i];
            csum[y * 40 + i] = acc;
            acc += v;
        }
        c.offs[y][n] = acc;
    }
}
__global__ void k_scanC(Csr4 c, const int* __restrict__ csum) {
    int y = blockIdx.y;
    int i = blockIdx.x * 256 + threadIdx.x;
    if (i < c.n[y]) {
        int v = c.offs[y][i] + csum[y * 40 + (i >> 10)];
        c.offs[y][i] = v;
        c.cur[y][i] = v;
    }
}
__global__ void k_scatter4(Csr4 c) {
    int y = blockIdx.y;
    int i = blockIdx.x * 256 + threadIdx.x;
    if (i < NE_) {
        int d = c.dst[y][i];
        int p = atomicAdd(&c.cur[y][d], 1);
        c.csr[y][p] = c.src[y][i];
    }
}

// ---------------- balanced flat f32 -> bf16 conversion (4 segments) ----------------
struct ConvF { const float* s[4]; unsigned short* d[4]; int cum[5]; };
__global__ void k_convf(ConvF cv) {
    int total = cv.cum[4];
    for (int i = blockIdx.x * 256 + threadIdx.x; i < total; i += gridDim.x * 256) {
        int y = (i >= cv.cum[1]) + (i >= cv.cum[2]) + (i >= cv.cum[3]);
        int j = i - cv.cum[y];
        float4 v = ((const float4*)cv.s[y])[j];
        ushort4 o;
        o.x = f2bf(v.x); o.y = f2bf(v.y); o.z = f2bf(v.z); o.w = f2bf(v.w);
        ((ushort4*)cv.d[y])[j] = o;
    }
}

// batched weight transpose+convert: dst[n*K+k] = bf16(a[k*N+n] (+ b[k*N+n]))
struct WItem { const float* a; const float* b; unsigned short* dst; int k; int n; };
struct WBatch { WItem it[16]; };
__global__ void k_wconvT(WBatch wb) {
    WItem w = wb.it[blockIdx.y];
    int total = w.k * w.n;
    int kmask = w.k - 1;
    int shift = (w.k == 1024) ? 10 : 8;
    for (int idx = blockIdx.x * 256 + threadIdx.x; idx < total; idx += gridDim.x * 256) {
        int k = idx & kmask, n = idx >> shift;
        float v = w.a[(size_t)k * w.n + n];
        if (w.b) v += w.b[(size_t)k * w.n + n];
        w.dst[idx] = f2bf(v);
    }
}

// ---------------- bf16 MFMA GEMM: C[M, gridDim.y*128] = A[M,K](lda) @ Bt[N,K]^T ----------------
template <bool OBF>
__global__ __launch_bounds__(256, 2) void k_gemm(
    const unsigned short* __restrict__ A, int lda,
    const unsigned short* __restrict__ Bt,
    void* __restrict__ Cv, int ldc, const float* __restrict__ bias,
    int M, int K)
{
    __shared__ __align__(16) unsigned short As[128 * 64];
    __shared__ __align__(16) unsigned short Bs[128 * 64];
    const int tid = threadIdx.x;
    const int lane = tid & 63;
    const int bm = blockIdx.x * 128;
    const int bn = blockIdx.y * 128;
    const int wave = tid >> 6;
    const int wr = (wave >> 1) * 64;
    const int wc = (wave & 1) * 64;
    const int frow = lane & 15;
    const int fkc = lane >> 4;
    f32x4 acc[4][4] = {};

    for (int k0 = 0; k0 < K; k0 += 64) {
        #pragma unroll
        for (int i = 0; i < 4; ++i) {
            int c = tid + i * 256;               // chunk 0..1023 (16B each)
            int row = c >> 3, kc = c & 7;
            int srck = k0 + ((kc ^ (row & 7)) << 3);  // pre-swizzled global source
            int ga = min(bm + row, M - 1);
            __builtin_amdgcn_global_load_lds(
                (const __attribute__((address_space(1))) unsigned int*)(A + (size_t)ga * lda + srck),
                (__attribute__((address_space(3))) unsigned int*)(As + (size_t)c * 8), 16, 0, 0);
            __builtin_amdgcn_global_load_lds(
                (const __attribute__((address_space(1))) unsigned int*)(Bt + (size_t)(bn + row) * K + srck),
                (__attribute__((address_space(3))) unsigned int*)(Bs + (size_t)c * 8), 16, 0, 0);
        }
        __syncthreads();
        #pragma unroll
        for (int kk = 0; kk < 2; ++kk) {
            bf16x8 af[4], bfr[4];
            #pragma unroll
            for (int m = 0; m < 4; ++m) {
                int row = wr + m * 16 + frow;
                int kc = kk * 4 + fkc;
                af[m] = *(const bf16x8*)(As + (size_t)((row << 3) + (kc ^ (row & 7))) * 8);
            }
            #pragma unroll
            for (int n = 0; n < 4; ++n) {
                int row = wc + n * 16 + frow;
                int kc = kk * 4 + fkc;
                bfr[n] = *(const bf16x8*)(Bs + (size_t)((row << 3) + (kc ^ (row & 7))) * 8);
            }
            #pragma unroll
            for (int m = 0; m < 4; ++m)
                #pragma unroll
                for (int n = 0; n < 4; ++n)
                    acc[m][n] = __builtin_amdgcn_mfma_f32_16x16x32_bf16(af[m], bfr[n], acc[m][n], 0, 0, 0);
        }
        __syncthreads();
    }

    const int orow0 = (lane >> 4) << 2;
    #pragma unroll
    for (int m = 0; m < 4; ++m) {
        #pragma unroll
        for (int r = 0; r < 4; ++r) {
            int row = bm + wr + m * 16 + orow0 + r;
            if (row < M) {
                #pragma unroll
                for (int n = 0; n < 4; ++n) {
                    int col = bn + wc + n * 16 + frow;
                    float v = acc[m][n][r];
                    if (bias) v += bias[col];
                    if constexpr (OBF)
                        ((unsigned short*)Cv)[(size_t)row * ldc + col] = f2bf(v);
                    else
                        ((float*)Cv)[(size_t)row * ldc + col] = v;
                }
            }
        }
    }
}

// ---------------- wave-per-node CSR mean-aggregate (bf16 RMW: outx += mean + bias) ----------------
__global__ __launch_bounds__(256) void k_aggw(const int* __restrict__ offs,
                                              const int* __restrict__ csr,
                                              const unsigned short* __restrict__ proj, int ldp,
                                              const float* __restrict__ bias,
                                              unsigned short* __restrict__ outx, int ldo,
                                              int ndst) {
    int node = blockIdx.x * 4 + (threadIdx.x >> 6);
    int lane = threadIdx.x & 63;
    if (node >= ndst) return;
    int beg = offs[node], end = offs[node + 1];
    float s0 = 0.f, s1 = 0.f, s2 = 0.f, s3 = 0.f;
    const unsigned short* base = proj + lane * 4;
    for (int e = beg; e < end; ++e) {
        int idx = csr[e];
        ushort4 u = *(const ushort4*)(base + (size_t)idx * ldp);
        s0 += bf2f(u.x); s1 += bf2f(u.y); s2 += bf2f(u.z); s3 += bf2f(u.w);
    }
    float inv = 1.f / fmaxf((float)(end - beg), 1.f);
    float4 b4 = ((const float4*)bias)[lane];
    size_t o = (size_t)node * ldo + lane * 4;
    ushort4 cur = *(const ushort4*)(outx + o);
    ushort4 w;
    w.x = f2bf(bf2f(cur.x) + s0 * inv + b4.x);
    w.y = f2bf(bf2f(cur.y) + s1 * inv + b4.y);
    w.z = f2bf(bf2f(cur.z) + s2 * inv + b4.z);
    w.w = f2bf(bf2f(cur.w) + s3 * inv + b4.w);
    *(ushort4*)(outx + o) = w;
}

// dual-source wave aggregate (reaction dst: p2r + m2r in one pass)
__global__ __launch_bounds__(256) void k_agg2w(const int* __restrict__ offsA,
                                               const int* __restrict__ csrA,
                                               const unsigned short* __restrict__ projA, int ldpA,
                                               const float* __restrict__ biasA,
                                               const int* __restrict__ offsB,
                                               const int* __restrict__ csrB,
                                               const unsigned short* __restrict__ projB, int ldpB,
                                               const float* __restrict__ biasB,
                                               unsigned short* __restrict__ outx, int ldo,
                                               int ndst) {
    int node = blockIdx.x * 4 + (threadIdx.x >> 6);
    int lane = threadIdx.x & 63;
    if (node >= ndst) return;
    float a0 = 0.f, a1 = 0.f, a2 = 0.f, a3 = 0.f;
    int begA = offsA[node], endA = offsA[node + 1];
    const unsigned short* baseA = projA + lane * 4;
    for (int e = begA; e < endA; ++e) {
        int idx = csrA[e];
        ushort4 u = *(const ushort4*)(baseA + (size_t)idx * ldpA);
        a0 += bf2f(u.x); a1 += bf2f(u.y); a2 += bf2f(u.z); a3 += bf2f(u.w);
    }
    float b0 = 0.f, b1 = 0.f, b2 = 0.f, b3 = 0.f;
    int begB = offsB[node], endB = offsB[node + 1];
    const unsigned short* baseB = projB + lane * 4;
    for (int e = begB; e < endB; ++e) {
        int idx = csrB[e];
        ushort4 u = *(const ushort4*)(baseB + (size_t)idx * ldpB);
        b0 += bf2f(u.x); b1 += bf2f(u.y); b2 += bf2f(u.z); b3 += bf2f(u.w);
    }
    float invA = 1.f / fmaxf((float)(endA - begA), 1.f);
    float invB = 1.f / fmaxf((float)(endB - begB), 1.f);
    float4 bA = ((const float4*)biasA)[lane];
    float4 bB = ((const float4*)biasB)[lane];
    size_t o = (size_t)node * ldo + lane * 4;
    ushort4 cur = *(const ushort4*)(outx + o);
    ushort4 w;
    w.x = f2bf(bf2f(cur.x) + a0 * invA + bA.x + b0 * invB + bB.x);
    w.y = f2bf(bf2f(cur.y) + a1 * invA + bA.y + b1 * invB + bB.y);
    w.z = f2bf(bf2f(cur.z) + a2 * invA + bA.z + b2 * invB + bB.z);
    w.w = f2bf(bf2f(cur.w) + a3 * invA + bA.w + b3 * invB + bB.w);
    *(ushort4*)(outx + o) = w;
}

// ---------------- cosine: one wave per row ----------------
__global__ __launch_bounds__(256) void k_cos(const float* __restrict__ ro,
                                             const float* __restrict__ pr,
                                             const int* __restrict__ types,
                                             float* __restrict__ out, int nr) {
    int row = blockIdx.x * 4 + (threadIdx.x >> 6);
    int lane = threadIdx.x & 63;
    if (row >= nr) return;
    int t = types[row];
    float2 r = ((const float2*)(ro + (size_t)row * OUTD_))[lane];
    float2 nn = ((const float2*)(pr + (size_t)row * 384 + t * OUTD_))[lane];
    float num = r.x * nn.x + r.y * nn.y;
    float d1 = r.x * r.x + r.y * r.y;
    float d2 = nn.x * nn.x + nn.y * nn.y;
    #pragma unroll
    for (int s = 1; s < 64; s <<= 1) {
        num += __shfl_xor(num, s);
        d1 += __shfl_xor(d1, s);
        d2 += __shfl_xor(d2, s);
    }
    if (lane == 0) out[row] = (num / fmaxf(sqrtf(d1) * sqrtf(d2), 1e-8f) + 1.f) * 0.5f;
}

extern "C" void kernel_launch(void* const* d_in, const int* in_sizes, int n_in,
                              void* d_out, int out_size, void* d_ws, size_t ws_size,
                              hipStream_t stream) {
    const float* x_r0 = (const float*)d_in[0];
    const float* x_p0 = (const float*)d_in[1];
    const float* x_m0 = (const float*)d_in[2];
    const int* e_src[4] = {(const int*)d_in[3], (const int*)d_in[5], (const int*)d_in[7], (const int*)d_in[9]};
    const int* e_dst[4] = {(const int*)d_in[4], (const int*)d_in[6], (const int*)d_in[8], (const int*)d_in[10]};
    const float* notes = (const float*)d_in[11];
    const int* types = (const int*)d_in[12];
    const float* Wl0 = (const float*)d_in[13];
    const float* Wr0 = (const float*)d_in[14];
    const float* bl0 = (const float*)d_in[15];
    const float* WlL = (const float*)d_in[16];
    const float* WrL = (const float*)d_in[17];
    const float* blL = (const float*)d_in[18];
    const float* Wre = (const float*)d_in[19];
    const float* bre = (const float*)d_in[20];
    const float* Wn  = (const float*)d_in[21];
    const float* bn  = (const float*)d_in[22];
    float* out = (float*)d_out;

    // ---- workspace carve ----
    uintptr_t base = (uintptr_t)d_ws;
    auto alloc = [&](size_t bytes) -> void* {
        uintptr_t p = (base + 255) & ~(uintptr_t)255;
        base = p + bytes;
        return (void*)p;
    };
    unsigned short* Rb[2] = {(unsigned short*)alloc((size_t)NR_ * 768 * 2),
                             (unsigned short*)alloc((size_t)NR_ * 768 * 2)};
    unsigned short* Pb[2] = {(unsigned short*)alloc((size_t)NP2_ * 512 * 2),
                             (unsigned short*)alloc((size_t)NP2_ * 512 * 2)};
    unsigned short* Mb[2] = {(unsigned short*)alloc((size_t)NM_ * 512 * 2),
                             (unsigned short*)alloc((size_t)NM_ * 512 * 2)};
    unsigned short* xr0bf = (unsigned short*)alloc((size_t)NR_ * EMB_ * 2);
    unsigned short* xp0bf = (unsigned short*)alloc((size_t)NP2_ * EMB_ * 2);
    unsigned short* xm0bf = (unsigned short*)alloc((size_t)NM_ * EMB_ * 2);
    unsigned short* notesbf = (unsigned short*)alloc((size_t)NR_ * EMB_ * 2);
    float* ro = (float*)alloc((size_t)NR_ * OUTD_ * 4);
    float* pr = (float*)alloc((size_t)NR_ * 384 * 4);
    unsigned short* wbf = (unsigned short*)alloc((size_t)4000000 * 2);
    int* csum = (int*)alloc(160 * 4);
    int nd[4] = {NR_, NR_, NP2_, NM_};
    Csr4 cs{};
    for (int t = 0; t < 4; ++t) {
        cs.src[t] = e_src[t]; cs.dst[t] = e_dst[t]; cs.n[t] = nd[t];
        cs.offs[t] = (int*)alloc(((size_t)nd[t] + 1) * 4);
        cs.cur[t]  = (int*)alloc((size_t)nd[t] * 4);
        cs.csr[t]  = (int*)alloc((size_t)NE_ * 4);
    }

    // ---- weight transpose+convert: concatenated B blocks, bf16 [N][K] ----
    unsigned short *BR[4], *BP[4], *BM[4], *Bre, *Bn;
    {
        WBatch b0{}, b1{};
        WItem* items[2] = {b0.it, b1.it};
        int cnt = 0;
        size_t woff = 0;
        auto add = [&](const float* a, const float* bb, int K, int N) -> unsigned short* {
            unsigned short* dst = wbf + woff;
            woff += (size_t)K * N;
            items[cnt >> 4][cnt & 15] = WItem{a, bb, dst, K, N};
            ++cnt;
            return dst;
        };
        const size_t w0 = (size_t)EMB_ * HID_;
        const size_t wl = (size_t)HID_ * HID_;
        for (int l = 0; l < 4; ++l) {
            int K = (l == 0) ? EMB_ : HID_;
            const float* Wr_ = (l == 0) ? Wr0 : WrL + (size_t)(l - 1) * 4 * wl;
            const float* Wl_ = (l == 0) ? Wl0 : WlL + (size_t)(l - 1) * 4 * wl;
            size_t ws_ = (l == 0) ? w0 : wl;
            BR[l] = add(Wr_ + 0 * ws_, Wr_ + 1 * ws_, K, HID_);  // WrC
            add(Wl_ + 2 * ws_, nullptr, K, HID_);                 // Wl2 (r2p proj)
            add(Wl_ + 3 * ws_, nullptr, K, HID_);                 // Wl3 (r2m proj)
            BP[l] = add(Wr_ + 2 * ws_, nullptr, K, HID_);         // Wr2
            add(Wl_ + 0 * ws_, nullptr, K, HID_);                 // Wl0 (p2r proj)
            BM[l] = add(Wr_ + 3 * ws_, nullptr, K, HID_);         // Wr3
            add(Wl_ + 1 * ws_, nullptr, K, HID_);                 // Wl1 (m2r proj)
        }
        Bre = add(Wre, nullptr, HID_, OUTD_);
        Bn = add(Wn + 0 * (size_t)EMB_ * OUTD_, nullptr, EMB_, OUTD_);
        add(Wn + 1 * (size_t)EMB_ * OUTD_, nullptr, EMB_, OUTD_);
        add(Wn + 2 * (size_t)EMB_ * OUTD_, nullptr, EMB_, OUTD_);
        k_wconvT<<<dim3(128, 16), 256, 0, stream>>>(b0);
        k_wconvT<<<dim3(128, cnt - 16), 256, 0, stream>>>(b1);
    }

    // ---- CSR build (batched over the 4 edge types) ----
    k_zero4<<<dim3((NP2_ + 255) / 256, 4), 256, 0, stream>>>(cs);
    k_deg4<<<dim3((NE_ + 255) / 256, 4), 256, 0, stream>>>(cs);
    k_scanA<<<dim3(40, 4), 256, 0, stream>>>(cs, csum);
    k_scanB<<<1, 64, 0, stream>>>(cs, csum);
    k_scanC<<<dim3((NP2_ + 255) / 256, 4), 256, 0, stream>>>(cs, csum);
    k_scatter4<<<dim3((NE_ + 255) / 256, 4), 256, 0, stream>>>(cs);

    // ---- input tables + notes -> bf16 (balanced flat) ----
    {
        ConvF cv{};
        cv.s[0] = x_r0; cv.d[0] = xr0bf;
        cv.s[1] = x_p0; cv.d[1] = xp0bf;
        cv.s[2] = x_m0; cv.d[2] = xm0bf;
        cv.s[3] = notes; cv.d[3] = notesbf;
        cv.cum[0] = 0;
        cv.cum[1] = NR_ * EMB_ / 4;
        cv.cum[2] = cv.cum[1] + NP2_ * EMB_ / 4;
        cv.cum[3] = cv.cum[2] + NM_ * EMB_ / 4;
        cv.cum[4] = cv.cum[3] + NR_ * EMB_ / 4;
        k_convf<<<4096, 256, 0, stream>>>(cv);
    }

    auto gemm_bf = [&](const unsigned short* A, int lda, const unsigned short* Bt,
                       unsigned short* C, int ldc, int M, int N, int K) {
        k_gemm<true><<<dim3((M + 127) / 128, N / 128), 256, 0, stream>>>(A, lda, Bt, C, ldc, nullptr, M, K);
    };

    for (int l = 0; l < 4; ++l) {
        int K = (l == 0) ? EMB_ : HID_;
        const unsigned short* axr = (l == 0) ? xr0bf : Rb[(l - 1) & 1];
        const unsigned short* axp = (l == 0) ? xp0bf : Pb[(l - 1) & 1];
        const unsigned short* axm = (l == 0) ? xm0bf : Mb[(l - 1) & 1];
        int lar = (l == 0) ? EMB_ : 768;
        int lapm = (l == 0) ? EMB_ : 512;
        unsigned short* R = Rb[l & 1];
        unsigned short* P = Pb[l & 1];
        unsigned short* M = Mb[l & 1];
        const float* bl_ = (l == 0) ? bl0 : blL + (size_t)(l - 1) * 4 * HID_;

        gemm_bf(axr, lar, BR[l], R, 768, NR_, 768, K);
        gemm_bf(axp, lapm, BP[l], P, 512, NP2_, 512, K);
        gemm_bf(axm, lapm, BM[l], M, 512, NM_, 512, K);

        // reaction <- mean(projP) + mean(projM); protein <- mean(projR); molecule <- mean(projR2)
        k_agg2w<<<(NR_ + 3) / 4, 256, 0, stream>>>(cs.offs[0], cs.csr[0], P + 256, 512, bl_ + 0 * HID_,
                                                   cs.offs[1], cs.csr[1], M + 256, 512, bl_ + 1 * HID_,
                                                   R, 768, NR_);
        k_aggw<<<(NP2_ + 3) / 4, 256, 0, stream>>>(cs.offs[2], cs.csr[2], R + 256, 768, bl_ + 2 * HID_, P, 512, NP2_);
        k_aggw<<<(NM_ + 3) / 4, 256, 0, stream>>>(cs.offs[3], cs.csr[3], R + 512, 768, bl_ + 3 * HID_, M, 512, NM_);
    }

    // ---- final: reaction proj (f32) + 3 node projs (f32, concatenated) + cosine ----
    k_gemm<false><<<dim3((NR_ + 127) / 128, 1), 256, 0, stream>>>(
        Rb[1], 768, Bre, ro, OUTD_, bre, NR_, HID_);
    k_gemm<false><<<dim3((NR_ + 127) / 128, 3), 256, 0, stream>>>(
        notesbf, EMB_, Bn, pr, 384, bn, NR_, EMB_);
    k_cos<<<NR_ / 4, 256, 0, stream>>>(ro, pr, types, out, NR_);
}

// Round 5
// 956.068 us; speedup vs baseline: 4.7276x; 1.0986x over previous
//
#include <hip/hip_runtime.h>
#include <math.h>
#include <stdint.h>

#define NR_ 16384
#define NP2_ 40000
#define NM_ 30000
#define NE_ 200000
#define EMB_ 1024
#define HID_ 256
#define OUTD_ 128

typedef __attribute__((ext_vector_type(8))) short bf16x8;
typedef __attribute__((ext_vector_type(4))) float f32x4;
typedef __attribute__((ext_vector_type(8))) unsigned short us8;

__device__ __forceinline__ unsigned short f2bf(float f) {
    uint32_t u = __builtin_bit_cast(uint32_t, f);
    u = (u + 0x7FFFu + ((u >> 16) & 1u)) >> 16;
    return (unsigned short)u;
}
__device__ __forceinline__ float bf2f(unsigned short u) {
    uint32_t v = ((uint32_t)u) << 16;
    return __builtin_bit_cast(float, v);
}

// ---------------- batched CSR build ----------------
struct Csr4 {
    const int* src[4]; const int* dst[4];
    int* offs[4]; int* cur[4]; int* csr[4];
    int n[4];
};
__global__ void k_zero4(Csr4 c) {
    int y = blockIdx.y;
    int i = blockIdx.x * 256 + threadIdx.x;
    if (i < c.n[y]) c.cur[y][i] = 0;
}
__global__ void k_deg4(Csr4 c) {
    int y = blockIdx.y;
    int i = blockIdx.x * 256 + threadIdx.x;
    if (i < NE_) atomicAdd(&c.cur[y][c.dst[y][i]], 1);
}
// two-level scan: A = per-1024-chunk block scan, B = chunk-sum scan, C = add base + init cur
__global__ void k_scanA(Csr4 c, int* __restrict__ csum) {
    int y = blockIdx.y;
    int n = c.n[y];
    int ch = blockIdx.x;
    int nch = (n + 1023) >> 10;
    if (ch >= nch) return;
    const int* deg = c.cur[y];
    int* offs = c.offs[y];
    __shared__ int ts[256];
    int base = ch << 10;
    int t = threadIdx.x;
    int v[4];
    int s = 0;
    #pragma unroll
    for (int k = 0; k < 4; ++k) {
        int i = base + t * 4 + k;
        v[k] = (i < n) ? deg[i] : 0;
        s += v[k];
    }
    ts[t] = s;
    __syncthreads();
    for (int st = 1; st < 256; st <<= 1) {
        int x = ts[t];
        int xo = (t >= st) ? ts[t - st] : 0;
        __syncthreads();
        ts[t] = x + xo;
        __syncthreads();
    }
    int run = (t > 0) ? ts[t - 1] : 0;
    #pragma unroll
    for (int k = 0; k < 4; ++k) {
        int i = base + t * 4 + k;
        if (i < n) offs[i] = run;
        run += v[k];
    }
    if (t == 255) csum[y * 40 + ch] = ts[255];
}
__global__ void k_scanB(Csr4 c, int* __restrict__ csum) {
    int y = threadIdx.x;
    if (y < 4) {
        int n = c.n[y];
        int nch = (n + 1023) >> 10;
        int acc = 0;
        for (int i = 0; i < nch; ++i) {
            int v = csum[y * 40 + i];
            csum[y * 40 + i] = acc;
            acc += v;
        }
        c.offs[y][n] = acc;
    }
}
__global__ void k_scanC(Csr4 c, const int* __restrict__ csum) {
    int y = blockIdx.y;
    int i = blockIdx.x * 256 + threadIdx.x;
    if (i < c.n[y]) {
        int v = c.offs[y][i] + csum[y * 40 + (i >> 10)];
        c.offs[y][i] = v;
        c.cur[y][i] = v;
    }
}
__global__ void k_scatter4(Csr4 c) {
    int y = blockIdx.y;
    int i = blockIdx.x * 256 + threadIdx.x;
    if (i < NE_) {
        int d = c.dst[y][i];
        int p = atomicAdd(&c.cur[y][d], 1);
        c.csr[y][p] = c.src[y][i];
    }
}

// ---------------- balanced flat f32 -> bf16 conversion (4 segments, 8 elem/thread) ----------------
struct ConvF { const float* s[4]; unsigned short* d[4]; int cum[5]; };
__global__ void k_convf(ConvF cv) {
    int total = cv.cum[4];   // in 8-element groups
    for (int i = blockIdx.x * 256 + threadIdx.x; i < total; i += gridDim.x * 256) {
        int y = (i >= cv.cum[1]) + (i >= cv.cum[2]) + (i >= cv.cum[3]);
        int j = i - cv.cum[y];
        const float4* sp = (const float4*)cv.s[y] + (size_t)j * 2;
        float4 v0 = sp[0];
        float4 v1 = sp[1];
        us8 o;
        o[0] = f2bf(v0.x); o[1] = f2bf(v0.y); o[2] = f2bf(v0.z); o[3] = f2bf(v0.w);
        o[4] = f2bf(v1.x); o[5] = f2bf(v1.y); o[6] = f2bf(v1.z); o[7] = f2bf(v1.w);
        ((us8*)cv.d[y])[j] = o;
    }
}

// batched weight transpose+convert: dst[n*K+k] = bf16(a[k*N+n] (+ b[k*N+n]))
struct WItem { const float* a; const float* b; unsigned short* dst; int k; int n; };
struct WBatch { WItem it[16]; };
__global__ void k_wconvT(WBatch wb) {
    WItem w = wb.it[blockIdx.y];
    int total = w.k * w.n;
    int kmask = w.k - 1;
    int shift = (w.k == 1024) ? 10 : 8;
    for (int idx = blockIdx.x * 256 + threadIdx.x; idx < total; idx += gridDim.x * 256) {
        int k = idx & kmask, n = idx >> shift;
        float v = w.a[(size_t)k * w.n + n];
        if (w.b) v += w.b[(size_t)k * w.n + n];
        w.dst[idx] = f2bf(v);
    }
}

// ---------------- bf16 MFMA GEMM: C[M, gridDim.y*128] = A[M,K](lda) @ Bt[N,K]^T ----------------
// Operand-swapped MFMA: D = mfma(bfr, af) so each lane holds 4 consecutive C columns
// -> packed ushort4 (bf16) / float4 (f32) stores.
template <bool OBF>
__global__ __launch_bounds__(256, 3) void k_gemm(
    const unsigned short* __restrict__ A, int lda,
    const unsigned short* __restrict__ Bt,
    void* __restrict__ Cv, int ldc, const float* __restrict__ bias,
    int M, int K)
{
    __shared__ __align__(16) unsigned short As[128 * 64];
    __shared__ __align__(16) unsigned short Bs[128 * 64];
    const int tid = threadIdx.x;
    const int lane = tid & 63;
    const int bm = blockIdx.x * 128;
    const int bn = blockIdx.y * 128;
    const int wave = tid >> 6;
    const int wr = (wave >> 1) * 64;
    const int wc = (wave & 1) * 64;
    const int frow = lane & 15;
    const int fkc = lane >> 4;
    f32x4 acc[4][4] = {};

    for (int k0 = 0; k0 < K; k0 += 64) {
        #pragma unroll
        for (int i = 0; i < 4; ++i) {
            int c = tid + i * 256;               // chunk 0..1023 (16B each)
            int row = c >> 3, kc = c & 7;
            int srck = k0 + ((kc ^ (row & 7)) << 3);  // pre-swizzled global source
            int ga = min(bm + row, M - 1);
            __builtin_amdgcn_global_load_lds(
                (const __attribute__((address_space(1))) unsigned int*)(A + (size_t)ga * lda + srck),
                (__attribute__((address_space(3))) unsigned int*)(As + (size_t)c * 8), 16, 0, 0);
            __builtin_amdgcn_global_load_lds(
                (const __attribute__((address_space(1))) unsigned int*)(Bt + (size_t)(bn + row) * K + srck),
                (__attribute__((address_space(3))) unsigned int*)(Bs + (size_t)c * 8), 16, 0, 0);
        }
        __syncthreads();
        #pragma unroll
        for (int kk = 0; kk < 2; ++kk) {
            bf16x8 af[4], bfr[4];
            #pragma unroll
            for (int m = 0; m < 4; ++m) {
                int row = wr + m * 16 + frow;
                int kc = kk * 4 + fkc;
                af[m] = *(const bf16x8*)(As + (size_t)((row << 3) + (kc ^ (row & 7))) * 8);
            }
            #pragma unroll
            for (int n = 0; n < 4; ++n) {
                int row = wc + n * 16 + frow;
                int kc = kk * 4 + fkc;
                bfr[n] = *(const bf16x8*)(Bs + (size_t)((row << 3) + (kc ^ (row & 7))) * 8);
            }
            #pragma unroll
            for (int m = 0; m < 4; ++m)
                #pragma unroll
                for (int n = 0; n < 4; ++n)
                    acc[m][n] = __builtin_amdgcn_mfma_f32_16x16x32_bf16(bfr[n], af[m], acc[m][n], 0, 0, 0);
        }
        __syncthreads();
    }

    // D = Bt_tile · A_tile^T: X-dim (reg, lane>>4) = C col, Y-dim (lane&15) = C row
    const int ccol0 = (lane >> 4) << 2;
    #pragma unroll
    for (int m = 0; m < 4; ++m) {
        int row = bm + wr + m * 16 + frow;
        if (row < M) {
            #pragma unroll
            for (int n = 0; n < 4; ++n) {
                int col = bn + wc + n * 16 + ccol0;
                f32x4 v = acc[m][n];
                if (bias) {
                    v[0] += bias[col + 0];
                    v[1] += bias[col + 1];
                    v[2] += bias[col + 2];
                    v[3] += bias[col + 3];
                }
                if constexpr (OBF) {
                    ushort4 o;
                    o.x = f2bf(v[0]); o.y = f2bf(v[1]); o.z = f2bf(v[2]); o.w = f2bf(v[3]);
                    *(ushort4*)((unsigned short*)Cv + (size_t)row * ldc + col) = o;
                } else {
                    *(float4*)((float*)Cv + (size_t)row * ldc + col) = make_float4(v[0], v[1], v[2], v[3]);
                }
            }
        }
    }
}

// ---------------- wave-per-node CSR mean-aggregate (bf16 RMW: outx += mean + bias) ----------------
__global__ __launch_bounds__(256) void k_aggw(const int* __restrict__ offs,
                                              const int* __restrict__ csr,
                                              const unsigned short* __restrict__ proj, int ldp,
                                              const float* __restrict__ bias,
                                              unsigned short* __restrict__ outx, int ldo,
                                              int ndst) {
    int node = blockIdx.x * 4 + (threadIdx.x >> 6);
    int lane = threadIdx.x & 63;
    if (node >= ndst) return;
    int beg = offs[node], end = offs[node + 1];
    float s0 = 0.f, s1 = 0.f, s2 = 0.f, s3 = 0.f;
    const unsigned short* base = proj + lane * 4;
    int e = beg;
    for (; e + 1 < end; e += 2) {
        int i0 = csr[e], i1 = csr[e + 1];
        ushort4 u0 = *(const ushort4*)(base + (size_t)i0 * ldp);
        ushort4 u1 = *(const ushort4*)(base + (size_t)i1 * ldp);
        s0 += bf2f(u0.x) + bf2f(u1.x);
        s1 += bf2f(u0.y) + bf2f(u1.y);
        s2 += bf2f(u0.z) + bf2f(u1.z);
        s3 += bf2f(u0.w) + bf2f(u1.w);
    }
    if (e < end) {
        ushort4 u = *(const ushort4*)(base + (size_t)csr[e] * ldp);
        s0 += bf2f(u.x); s1 += bf2f(u.y); s2 += bf2f(u.z); s3 += bf2f(u.w);
    }
    float inv = 1.f / fmaxf((float)(end - beg), 1.f);
    float4 b4 = ((const float4*)bias)[lane];
    size_t o = (size_t)node * ldo + lane * 4;
    ushort4 cur = *(const ushort4*)(outx + o);
    ushort4 w;
    w.x = f2bf(bf2f(cur.x) + s0 * inv + b4.x);
    w.y = f2bf(bf2f(cur.y) + s1 * inv + b4.y);
    w.z = f2bf(bf2f(cur.z) + s2 * inv + b4.z);
    w.w = f2bf(bf2f(cur.w) + s3 * inv + b4.w);
    *(ushort4*)(outx + o) = w;
}

// dual-source wave aggregate (reaction dst: p2r + m2r in one pass)
__global__ __launch_bounds__(256) void k_agg2w(const int* __restrict__ offsA,
                                               const int* __restrict__ csrA,
                                               const unsigned short* __restrict__ projA, int ldpA,
                                               const float* __restrict__ biasA,
                                               const int* __restrict__ offsB,
                                               const int* __restrict__ csrB,
                                               const unsigned short* __restrict__ projB, int ldpB,
                                               const float* __restrict__ biasB,
                                               unsigned short* __restrict__ outx, int ldo,
                                               int ndst) {
    int node = blockIdx.x * 4 + (threadIdx.x >> 6);
    int lane = threadIdx.x & 63;
    if (node >= ndst) return;
    float a0 = 0.f, a1 = 0.f, a2 = 0.f, a3 = 0.f;
    int begA = offsA[node], endA = offsA[node + 1];
    const unsigned short* baseA = projA + lane * 4;
    int e = begA;
    for (; e + 1 < endA; e += 2) {
        int i0 = csrA[e], i1 = csrA[e + 1];
        ushort4 u0 = *(const ushort4*)(baseA + (size_t)i0 * ldpA);
        ushort4 u1 = *(const ushort4*)(baseA + (size_t)i1 * ldpA);
        a0 += bf2f(u0.x) + bf2f(u1.x);
        a1 += bf2f(u0.y) + bf2f(u1.y);
        a2 += bf2f(u0.z) + bf2f(u1.z);
        a3 += bf2f(u0.w) + bf2f(u1.w);
    }
    if (e < endA) {
        ushort4 u = *(const ushort4*)(baseA + (size_t)csrA[e] * ldpA);
        a0 += bf2f(u.x); a1 += bf2f(u.y); a2 += bf2f(u.z); a3 += bf2f(u.w);
    }
    float b0 = 0.f, b1 = 0.f, b2 = 0.f, b3 = 0.f;
    int begB = offsB[node], endB = offsB[node + 1];
    const unsigned short* baseB = projB + lane * 4;
    e = begB;
    for (; e + 1 < endB; e += 2) {
        int i0 = csrB[e], i1 = csrB[e + 1];
        ushort4 u0 = *(const ushort4*)(baseB + (size_t)i0 * ldpB);
        ushort4 u1 = *(const ushort4*)(baseB + (size_t)i1 * ldpB);
        b0 += bf2f(u0.x) + bf2f(u1.x);
        b1 += bf2f(u0.y) + bf2f(u1.y);
        b2 += bf2f(u0.z) + bf2f(u1.z);
        b3 += bf2f(u0.w) + bf2f(u1.w);
    }
    if (e < endB) {
        ushort4 u = *(const ushort4*)(baseB + (size_t)csrB[e] * ldpB);
        b0 += bf2f(u.x); b1 += bf2f(u.y); b2 += bf2f(u.z); b3 += bf2f(u.w);
    }
    float invA = 1.f / fmaxf((float)(endA - begA), 1.f);
    float invB = 1.f / fmaxf((float)(endB - begB), 1.f);
    float4 bA = ((const float4*)biasA)[lane];
    float4 bB = ((const float4*)biasB)[lane];
    size_t o = (size_t)node * ldo + lane * 4;
    ushort4 cur = *(const ushort4*)(outx + o);
    ushort4 w;
    w.x = f2bf(bf2f(cur.x) + a0 * invA + bA.x + b0 * invB + bB.x);
    w.y = f2bf(bf2f(cur.y) + a1 * invA + bA.y + b1 * invB + bB.y);
    w.z = f2bf(bf2f(cur.z) + a2 * invA + bA.z + b2 * invB + bB.z);
    w.w = f2bf(bf2f(cur.w) + a3 * invA + bA.w + b3 * invB + bB.w);
    *(ushort4*)(outx + o) = w;
}

// ---------------- cosine: one wave per row ----------------
__global__ __launch_bounds__(256) void k_cos(const float* __restrict__ ro,
                                             const float* __restrict__ pr,
                                             const int* __restrict__ types,
                                             float* __restrict__ out, int nr) {
    int row = blockIdx.x * 4 + (threadIdx.x >> 6);
    int lane = threadIdx.x & 63;
    if (row >= nr) return;
    int t = types[row];
    float2 r = ((const float2*)(ro + (size_t)row * OUTD_))[lane];
    float2 nn = ((const float2*)(pr + (size_t)row * 384 + t * OUTD_))[lane];
    float num = r.x * nn.x + r.y * nn.y;
    float d1 = r.x * r.x + r.y * r.y;
    float d2 = nn.x * nn.x + nn.y * nn.y;
    #pragma unroll
    for (int s = 1; s < 64; s <<= 1) {
        num += __shfl_xor(num, s);
        d1 += __shfl_xor(d1, s);
        d2 += __shfl_xor(d2, s);
    }
    if (lane == 0) out[row] = (num / fmaxf(sqrtf(d1) * sqrtf(d2), 1e-8f) + 1.f) * 0.5f;
}

extern "C" void kernel_launch(void* const* d_in, const int* in_sizes, int n_in,
                              void* d_out, int out_size, void* d_ws, size_t ws_size,
                              hipStream_t stream) {
    const float* x_r0 = (const float*)d_in[0];
    const float* x_p0 = (const float*)d_in[1];
    const float* x_m0 = (const float*)d_in[2];
    const int* e_src[4] = {(const int*)d_in[3], (const int*)d_in[5], (const int*)d_in[7], (const int*)d_in[9]};
    const int* e_dst[4] = {(const int*)d_in[4], (const int*)d_in[6], (const int*)d_in[8], (const int*)d_in[10]};
    const float* notes = (const float*)d_in[11];
    const int* types = (const int*)d_in[12];
    const float* Wl0 = (const float*)d_in[13];
    const float* Wr0 = (const float*)d_in[14];
    const float* bl0 = (const float*)d_in[15];
    const float* WlL = (const float*)d_in[16];
    const float* WrL = (const float*)d_in[17];
    const float* blL = (const float*)d_in[18];
    const float* Wre = (const float*)d_in[19];
    const float* bre = (const float*)d_in[20];
    const float* Wn  = (const float*)d_in[21];
    const float* bn  = (const float*)d_in[22];
    float* out = (float*)d_out;

    // ---- workspace carve ----
    uintptr_t base = (uintptr_t)d_ws;
    auto alloc = [&](size_t bytes) -> void* {
        uintptr_t p = (base + 255) & ~(uintptr_t)255;
        base = p + bytes;
        return (void*)p;
    };
    unsigned short* Rb[2] = {(unsigned short*)alloc((size_t)NR_ * 768 * 2),
                             (unsigned short*)alloc((size_t)NR_ * 768 * 2)};
    unsigned short* Pb[2] = {(unsigned short*)alloc((size_t)NP2_ * 512 * 2),
                             (unsigned short*)alloc((size_t)NP2_ * 512 * 2)};
    unsigned short* Mb[2] = {(unsigned short*)alloc((size_t)NM_ * 512 * 2),
                             (unsigned short*)alloc((size_t)NM_ * 512 * 2)};
    unsigned short* xr0bf = (unsigned short*)alloc((size_t)NR_ * EMB_ * 2);
    unsigned short* xp0bf = (unsigned short*)alloc((size_t)NP2_ * EMB_ * 2);
    unsigned short* xm0bf = (unsigned short*)alloc((size_t)NM_ * EMB_ * 2);
    unsigned short* notesbf = (unsigned short*)alloc((size_t)NR_ * EMB_ * 2);
    float* ro = (float*)alloc((size_t)NR_ * OUTD_ * 4);
    float* pr = (float*)alloc((size_t)NR_ * 384 * 4);
    unsigned short* wbf = (unsigned short*)alloc((size_t)4000000 * 2);
    int* csum = (int*)alloc(160 * 4);
    int nd[4] = {NR_, NR_, NP2_, NM_};
    Csr4 cs{};
    for (int t = 0; t < 4; ++t) {
        cs.src[t] = e_src[t]; cs.dst[t] = e_dst[t]; cs.n[t] = nd[t];
        cs.offs[t] = (int*)alloc(((size_t)nd[t] + 1) * 4);
        cs.cur[t]  = (int*)alloc((size_t)nd[t] * 4);
        cs.csr[t]  = (int*)alloc((size_t)NE_ * 4);
    }

    // ---- weight transpose+convert: concatenated B blocks, bf16 [N][K] ----
    unsigned short *BR[4], *BP[4], *BM[4], *Bre, *Bn;
    {
        WBatch b0{}, b1{};
        WItem* items[2] = {b0.it, b1.it};
        int cnt = 0;
        size_t woff = 0;
        auto add = [&](const float* a, const float* bb, int K, int N) -> unsigned short* {
            unsigned short* dst = wbf + woff;
            woff += (size_t)K * N;
            items[cnt >> 4][cnt & 15] = WItem{a, bb, dst, K, N};
            ++cnt;
            return dst;
        };
        const size_t w0 = (size_t)EMB_ * HID_;
        const size_t wl = (size_t)HID_ * HID_;
        for (int l = 0; l < 4; ++l) {
            int K = (l == 0) ? EMB_ : HID_;
            const float* Wr_ = (l == 0) ? Wr0 : WrL + (size_t)(l - 1) * 4 * wl;
            const float* Wl_ = (l == 0) ? Wl0 : WlL + (size_t)(l - 1) * 4 * wl;
            size_t ws_ = (l == 0) ? w0 : wl;
            BR[l] = add(Wr_ + 0 * ws_, Wr_ + 1 * ws_, K, HID_);  // WrC
            add(Wl_ + 2 * ws_, nullptr, K, HID_);                 // Wl2 (r2p proj)
            add(Wl_ + 3 * ws_, nullptr, K, HID_);                 // Wl3 (r2m proj)
            BP[l] = add(Wr_ + 2 * ws_, nullptr, K, HID_);         // Wr2
            add(Wl_ + 0 * ws_, nullptr, K, HID_);                 // Wl0 (p2r proj)
            BM[l] = add(Wr_ + 3 * ws_, nullptr, K, HID_);         // Wr3
            add(Wl_ + 1 * ws_, nullptr, K, HID_);                 // Wl1 (m2r proj)
        }
        Bre = add(Wre, nullptr, HID_, OUTD_);
        Bn = add(Wn + 0 * (size_t)EMB_ * OUTD_, nullptr, EMB_, OUTD_);
        add(Wn + 1 * (size_t)EMB_ * OUTD_, nullptr, EMB_, OUTD_);
        add(Wn + 2 * (size_t)EMB_ * OUTD_, nullptr, EMB_, OUTD_);
        k_wconvT<<<dim3(128, 16), 256, 0, stream>>>(b0);
        k_wconvT<<<dim3(128, cnt - 16), 256, 0, stream>>>(b1);
    }

    // ---- CSR build (batched over the 4 edge types) ----
    k_zero4<<<dim3((NP2_ + 255) / 256, 4), 256, 0, stream>>>(cs);
    k_deg4<<<dim3((NE_ + 255) / 256, 4), 256, 0, stream>>>(cs);
    k_scanA<<<dim3(40, 4), 256, 0, stream>>>(cs, csum);
    k_scanB<<<1, 64, 0, stream>>>(cs, csum);
    k_scanC<<<dim3((NP2_ + 255) / 256, 4), 256, 0, stream>>>(cs, csum);
    k_scatter4<<<dim3((NE_ + 255) / 256, 4), 256, 0, stream>>>(cs);

    // ---- input tables + notes -> bf16 (balanced flat, 8 elem/thread) ----
    {
        ConvF cv{};
        cv.s[0] = x_r0; cv.d[0] = xr0bf;
        cv.s[1] = x_p0; cv.d[1] = xp0bf;
        cv.s[2] = x_m0; cv.d[2] = xm0bf;
        cv.s[3] = notes; cv.d[3] = notesbf;
        cv.cum[0] = 0;
        cv.cum[1] = NR_ * EMB_ / 8;
        cv.cum[2] = cv.cum[1] + NP2_ * EMB_ / 8;
        cv.cum[3] = cv.cum[2] + NM_ * EMB_ / 8;
        cv.cum[4] = cv.cum[3] + NR_ * EMB_ / 8;
        k_convf<<<4096, 256, 0, stream>>>(cv);
    }

    auto gemm_bf = [&](const unsigned short* A, int lda, const unsigned short* Bt,
                       unsigned short* C, int ldc, int M, int N, int K) {
        k_gemm<true><<<dim3((M + 127) / 128, N / 128), 256, 0, stream>>>(A, lda, Bt, C, ldc, nullptr, M, K);
    };

    for (int l = 0; l < 4; ++l) {
        int K = (l == 0) ? EMB_ : HID_;
        const unsigned short* axr = (l == 0) ? xr0bf : Rb[(l - 1) & 1];
        const unsigned short* axp = (l == 0) ? xp0bf : Pb[(l - 1) & 1];
        const unsigned short* axm = (l == 0) ? xm0bf : Mb[(l - 1) & 1];
        int lar = (l == 0) ? EMB_ : 768;
        int lapm = (l == 0) ? EMB_ : 512;
        unsigned short* R = Rb[l & 1];
        unsigned short* P = Pb[l & 1];
        unsigned short* M = Mb[l & 1];
        const float* bl_ = (l == 0) ? bl0 : blL + (size_t)(l - 1) * 4 * HID_;

        gemm_bf(axr, lar, BR[l], R, 768, NR_, 768, K);
        gemm_bf(axp, lapm, BP[l], P, 512, NP2_, 512, K);
        gemm_bf(axm, lapm, BM[l], M, 512, NM_, 512, K);

        // reaction <- mean(projP) + mean(projM); protein <- mean(projR); molecule <- mean(projR2)
        k_agg2w<<<(NR_ + 3) / 4, 256, 0, stream>>>(cs.offs[0], cs.csr[0], P + 256, 512, bl_ + 0 * HID_,
                                                   cs.offs[1], cs.csr[1], M + 256, 512, bl_ + 1 * HID_,
                                                   R, 768, NR_);
        k_aggw<<<(NP2_ + 3) / 4, 256, 0, stream>>>(cs.offs[2], cs.csr[2], R + 256, 768, bl_ + 2 * HID_, P, 512, NP2_);
        k_aggw<<<(NM_ + 3) / 4, 256, 0, stream>>>(cs.offs[3], cs.csr[3], R + 512, 768, bl_ + 3 * HID_, M, 512, NM_);
    }

    // ---- final: reaction proj (f32) + 3 node projs (f32, concatenated) + cosine ----
    k_gemm<false><<<dim3((NR_ + 127) / 128, 1), 256, 0, stream>>>(
        Rb[1], 768, Bre, ro, OUTD_, bre, NR_, HID_);
    k_gemm<false><<<dim3((NR_ + 127) / 128, 3), 256, 0, stream>>>(
        notesbf, EMB_, Bn, pr, 384, bn, NR_, EMB_);
    k_cos<<<NR_ / 4, 256, 0, stream>>>(ro, pr, types, out, NR_);
}

// Round 6
// 887.869 us; speedup vs baseline: 5.0908x; 1.0768x over previous
//
#include <hip/hip_runtime.h>
#include <math.h>
#include <stdint.h>

#define NR_ 16384
#define NP2_ 40000
#define NM_ 30000
#define NE_ 200000
#define EMB_ 1024
#define HID_ 256
#define OUTD_ 128

typedef __attribute__((ext_vector_type(8))) short bf16x8;
typedef __attribute__((ext_vector_type(4))) float f32x4;
typedef __attribute__((ext_vector_type(8))) unsigned short us8;

__device__ __forceinline__ unsigned short f2bf(float f) {
    uint32_t u = __builtin_bit_cast(uint32_t, f);
    u = (u + 0x7FFFu + ((u >> 16) & 1u)) >> 16;
    return (unsigned short)u;
}
__device__ __forceinline__ float bf2f(unsigned short u) {
    uint32_t v = ((uint32_t)u) << 16;
    return __builtin_bit_cast(float, v);
}

// ---------------- batched CSR build ----------------
struct Csr4 {
    const int* src[4]; const int* dst[4];
    int* offs[4]; int* cur[4]; int* csr[4];
    int n[4];
};
__global__ void k_zero4(Csr4 c) {
    int y = blockIdx.y;
    int i = blockIdx.x * 256 + threadIdx.x;
    if (i < c.n[y]) c.cur[y][i] = 0;
}
__global__ void k_deg4(Csr4 c) {
    int y = blockIdx.y;
    int i = blockIdx.x * 256 + threadIdx.x;
    if (i < NE_) atomicAdd(&c.cur[y][c.dst[y][i]], 1);
}
// two-level scan: A = per-1024-chunk block scan, B = chunk-sum scan, C = add base + init cur
__global__ void k_scanA(Csr4 c, int* __restrict__ csum) {
    int y = blockIdx.y;
    int n = c.n[y];
    int ch = blockIdx.x;
    int nch = (n + 1023) >> 10;
    if (ch >= nch) return;
    const int* deg = c.cur[y];
    int* offs = c.offs[y];
    __shared__ int ts[256];
    int base = ch << 10;
    int t = threadIdx.x;
    int v[4];
    int s = 0;
    #pragma unroll
    for (int k = 0; k < 4; ++k) {
        int i = base + t * 4 + k;
        v[k] = (i < n) ? deg[i] : 0;
        s += v[k];
    }
    ts[t] = s;
    __syncthreads();
    for (int st = 1; st < 256; st <<= 1) {
        int x = ts[t];
        int xo = (t >= st) ? ts[t - st] : 0;
        __syncthreads();
        ts[t] = x + xo;
        __syncthreads();
    }
    int run = (t > 0) ? ts[t - 1] : 0;
    #pragma unroll
    for (int k = 0; k < 4; ++k) {
        int i = base + t * 4 + k;
        if (i < n) offs[i] = run;
        run += v[k];
    }
    if (t == 255) csum[y * 40 + ch] = ts[255];
}
__global__ void k_scanB(Csr4 c, int* __restrict__ csum) {
    int y = threadIdx.x;
    if (y < 4) {
        int n = c.n[y];
        int nch = (n + 1023) >> 10;
        int acc = 0;
        for (int i = 0; i < nch; ++i) {
            int v = csum[y * 40 + i];
            csum[y * 40 + i] = acc;
            acc += v;
        }
        c.offs[y][n] = acc;
    }
}
__global__ void k_scanC(Csr4 c, const int* __restrict__ csum) {
    int y = blockIdx.y;
    int i = blockIdx.x * 256 + threadIdx.x;
    if (i < c.n[y]) {
        int v = c.offs[y][i] + csum[y * 40 + (i >> 10)];
        c.offs[y][i] = v;
        c.cur[y][i] = v;
    }
}
__global__ void k_scatter4(Csr4 c) {
    int y = blockIdx.y;
    int i = blockIdx.x * 256 + threadIdx.x;
    if (i < NE_) {
        int d = c.dst[y][i];
        int p = atomicAdd(&c.cur[y][d], 1);
        c.csr[y][p] = c.src[y][i];
    }
}

// batched weight transpose+convert: dst[n*K+k] = bf16(a[k*N+n] (+ b[k*N+n]))
struct WItem { const float* a; const float* b; unsigned short* dst; int k; int n; };
struct WBatch { WItem it[32]; };
__global__ void k_wconvT(WBatch wb) {
    WItem w = wb.it[blockIdx.y];
    int total = w.k * w.n;
    int kmask = w.k - 1;
    int shift = (w.k == 1024) ? 10 : 8;
    for (int idx = blockIdx.x * 256 + threadIdx.x; idx < total; idx += gridDim.x * 256) {
        int k = idx & kmask, n = idx >> shift;
        float v = w.a[(size_t)k * w.n + n];
        if (w.b) v += w.b[(size_t)k * w.n + n];
        w.dst[idx] = f2bf(v);
    }
}

// ---------------- bf16 MFMA GEMM: C[M, Ntiles*128] = A[M,K](lda) @ Bt[N,K]^T ----------------
// AF32: A is f32, reg-staged + converted to bf16 during LDS write (same swizzled layout).
// Grid: launched (Mtiles, Ntiles); flattened + bijective XCD-chunk remap, col-tile fastest
// so consecutive blocks on an XCD share the same A row-panel (L2 reuse).
// Operand-swapped MFMA: D = mfma(bfr, af) -> lane holds 4 consecutive C columns (packed stores).
template <bool OBF, bool AF32>
__global__ __launch_bounds__(256, 3) void k_gemm(
    const void* __restrict__ Av, int lda,
    const unsigned short* __restrict__ Bt,
    void* __restrict__ Cv, int ldc, const float* __restrict__ bias,
    int M, int K)
{
    __shared__ __align__(16) unsigned short As[128 * 64];
    __shared__ __align__(16) unsigned short Bs[128 * 64];
    const int tid = threadIdx.x;
    const int lane = tid & 63;
    // ---- XCD-chunk swizzle, col-tile fastest ----
    int nwg = gridDim.x * gridDim.y;
    int o = blockIdx.y * gridDim.x + blockIdx.x;
    int q = nwg >> 3, r = nwg & 7;
    int xcd = o & 7, j = o >> 3;
    int wg = (xcd < r ? xcd * (q + 1) : r * (q + 1) + (xcd - r) * q) + j;
    const int bm = (wg / gridDim.y) * 128;
    const int bn = (wg % gridDim.y) * 128;
    const int wave = tid >> 6;
    const int wr = (wave >> 1) * 64;
    const int wc = (wave & 1) * 64;
    const int frow = lane & 15;
    const int fkc = lane >> 4;
    f32x4 acc[4][4] = {};

    for (int k0 = 0; k0 < K; k0 += 64) {
        #pragma unroll
        for (int i = 0; i < 4; ++i) {
            int c = tid + i * 256;               // chunk 0..1023 (16B each)
            int row = c >> 3, kc = c & 7;
            int srck = k0 + ((kc ^ (row & 7)) << 3);  // pre-swizzled global source
            int ga = min(bm + row, M - 1);
            if constexpr (AF32) {
                const float* Af = (const float*)Av + (size_t)ga * lda + srck;
                float4 a0 = *(const float4*)Af;
                float4 a1 = *(const float4*)(Af + 4);
                us8 oo;
                oo[0] = f2bf(a0.x); oo[1] = f2bf(a0.y); oo[2] = f2bf(a0.z); oo[3] = f2bf(a0.w);
                oo[4] = f2bf(a1.x); oo[5] = f2bf(a1.y); oo[6] = f2bf(a1.z); oo[7] = f2bf(a1.w);
                *(us8*)(As + (size_t)c * 8) = oo;
            } else {
                __builtin_amdgcn_global_load_lds(
                    (const __attribute__((address_space(1))) unsigned int*)((const unsigned short*)Av + (size_t)ga * lda + srck),
                    (__attribute__((address_space(3))) unsigned int*)(As + (size_t)c * 8), 16, 0, 0);
            }
            __builtin_amdgcn_global_load_lds(
                (const __attribute__((address_space(1))) unsigned int*)(Bt + (size_t)(bn + row) * K + srck),
                (__attribute__((address_space(3))) unsigned int*)(Bs + (size_t)c * 8), 16, 0, 0);
        }
        __syncthreads();
        #pragma unroll
        for (int kk = 0; kk < 2; ++kk) {
            bf16x8 af[4], bfr[4];
            #pragma unroll
            for (int m = 0; m < 4; ++m) {
                int row = wr + m * 16 + frow;
                int kc = kk * 4 + fkc;
                af[m] = *(const bf16x8*)(As + (size_t)((row << 3) + (kc ^ (row & 7))) * 8);
            }
            #pragma unroll
            for (int n = 0; n < 4; ++n) {
                int row = wc + n * 16 + frow;
                int kc = kk * 4 + fkc;
                bfr[n] = *(const bf16x8*)(Bs + (size_t)((row << 3) + (kc ^ (row & 7))) * 8);
            }
            #pragma unroll
            for (int m = 0; m < 4; ++m)
                #pragma unroll
                for (int n = 0; n < 4; ++n)
                    acc[m][n] = __builtin_amdgcn_mfma_f32_16x16x32_bf16(bfr[n], af[m], acc[m][n], 0, 0, 0);
        }
        __syncthreads();
    }

    // D = Bt_tile · A_tile^T: X-dim (lane>>4, reg) = C col, Y-dim (lane&15) = C row
    const int ccol0 = (lane >> 4) << 2;
    #pragma unroll
    for (int m = 0; m < 4; ++m) {
        int row = bm + wr + m * 16 + frow;
        if (row < M) {
            #pragma unroll
            for (int n = 0; n < 4; ++n) {
                int col = bn + wc + n * 16 + ccol0;
                f32x4 v = acc[m][n];
                if (bias) {
                    v[0] += bias[col + 0];
                    v[1] += bias[col + 1];
                    v[2] += bias[col + 2];
                    v[3] += bias[col + 3];
                }
                if constexpr (OBF) {
                    ushort4 oo;
                    oo.x = f2bf(v[0]); oo.y = f2bf(v[1]); oo.z = f2bf(v[2]); oo.w = f2bf(v[3]);
                    *(ushort4*)((unsigned short*)Cv + (size_t)row * ldc + col) = oo;
                } else {
                    *(float4*)((float*)Cv + (size_t)row * ldc + col) = make_float4(v[0], v[1], v[2], v[3]);
                }
            }
        }
    }
}

// ---------------- wave-per-node CSR mean-aggregate (bf16 RMW: outx += mean + bias) ----------------
__global__ __launch_bounds__(256) void k_aggw(const int* __restrict__ offs,
                                              const int* __restrict__ csr,
                                              const unsigned short* __restrict__ proj, int ldp,
                                              const float* __restrict__ bias,
                                              unsigned short* __restrict__ outx, int ldo,
                                              int ndst) {
    int node = blockIdx.x * 4 + (threadIdx.x >> 6);
    int lane = threadIdx.x & 63;
    if (node >= ndst) return;
    int beg = offs[node], end = offs[node + 1];
    float s0 = 0.f, s1 = 0.f, s2 = 0.f, s3 = 0.f;
    const unsigned short* base = proj + lane * 4;
    int e = beg;
    for (; e + 1 < end; e += 2) {
        int i0 = csr[e], i1 = csr[e + 1];
        ushort4 u0 = *(const ushort4*)(base + (size_t)i0 * ldp);
        ushort4 u1 = *(const ushort4*)(base + (size_t)i1 * ldp);
        s0 += bf2f(u0.x) + bf2f(u1.x);
        s1 += bf2f(u0.y) + bf2f(u1.y);
        s2 += bf2f(u0.z) + bf2f(u1.z);
        s3 += bf2f(u0.w) + bf2f(u1.w);
    }
    if (e < end) {
        ushort4 u = *(const ushort4*)(base + (size_t)csr[e] * ldp);
        s0 += bf2f(u.x); s1 += bf2f(u.y); s2 += bf2f(u.z); s3 += bf2f(u.w);
    }
    float inv = 1.f / fmaxf((float)(end - beg), 1.f);
    float4 b4 = ((const float4*)bias)[lane];
    size_t o = (size_t)node * ldo + lane * 4;
    ushort4 cur = *(const ushort4*)(outx + o);
    ushort4 w;
    w.x = f2bf(bf2f(cur.x) + s0 * inv + b4.x);
    w.y = f2bf(bf2f(cur.y) + s1 * inv + b4.y);
    w.z = f2bf(bf2f(cur.z) + s2 * inv + b4.z);
    w.w = f2bf(bf2f(cur.w) + s3 * inv + b4.w);
    *(ushort4*)(outx + o) = w;
}

// dual-source wave aggregate (reaction dst: p2r + m2r in one pass)
__global__ __launch_bounds__(256) void k_agg2w(const int* __restrict__ offsA,
                                               const int* __restrict__ csrA,
                                               const unsigned short* __restrict__ projA, int ldpA,
                                               const float* __restrict__ biasA,
                                               const int* __restrict__ offsB,
                                               const int* __restrict__ csrB,
                                               const unsigned short* __restrict__ projB, int ldpB,
                                               const float* __restrict__ biasB,
                                               unsigned short* __restrict__ outx, int ldo,
                                               int ndst) {
    int node = blockIdx.x * 4 + (threadIdx.x >> 6);
    int lane = threadIdx.x & 63;
    if (node >= ndst) return;
    float a0 = 0.f, a1 = 0.f, a2 = 0.f, a3 = 0.f;
    int begA = offsA[node], endA = offsA[node + 1];
    const unsigned short* baseA = projA + lane * 4;
    int e = begA;
    for (; e + 1 < endA; e += 2) {
        int i0 = csrA[e], i1 = csrA[e + 1];
        ushort4 u0 = *(const ushort4*)(baseA + (size_t)i0 * ldpA);
        ushort4 u1 = *(const ushort4*)(baseA + (size_t)i1 * ldpA);
        a0 += bf2f(u0.x) + bf2f(u1.x);
        a1 += bf2f(u0.y) + bf2f(u1.y);
        a2 += bf2f(u0.z) + bf2f(u1.z);
        a3 += bf2f(u0.w) + bf2f(u1.w);
    }
    if (e < endA) {
        ushort4 u = *(const ushort4*)(baseA + (size_t)csrA[e] * ldpA);
        a0 += bf2f(u.x); a1 += bf2f(u.y); a2 += bf2f(u.z); a3 += bf2f(u.w);
    }
    float b0 = 0.f, b1 = 0.f, b2 = 0.f, b3 = 0.f;
    int begB = offsB[node], endB = offsB[node + 1];
    const unsigned short* baseB = projB + lane * 4;
    e = begB;
    for (; e + 1 < endB; e += 2) {
        int i0 = csrB[e], i1 = csrB[e + 1];
        ushort4 u0 = *(const ushort4*)(baseB + (size_t)i0 * ldpB);
        ushort4 u1 = *(const ushort4*)(baseB + (size_t)i1 * ldpB);
        b0 += bf2f(u0.x) + bf2f(u1.x);
        b1 += bf2f(u0.y) + bf2f(u1.y);
        b2 += bf2f(u0.z) + bf2f(u1.z);
        b3 += bf2f(u0.w) + bf2f(u1.w);
    }
    if (e < endB) {
        ushort4 u = *(const ushort4*)(baseB + (size_t)csrB[e] * ldpB);
        b0 += bf2f(u.x); b1 += bf2f(u.y); b2 += bf2f(u.z); b3 += bf2f(u.w);
    }
    float invA = 1.f / fmaxf((float)(endA - begA), 1.f);
    float invB = 1.f / fmaxf((float)(endB - begB), 1.f);
    float4 bA = ((const float4*)biasA)[lane];
    float4 bB = ((const float4*)biasB)[lane];
    size_t o = (size_t)node * ldo + lane * 4;
    ushort4 cur = *(const ushort4*)(outx + o);
    ushort4 w;
    w.x = f2bf(bf2f(cur.x) + a0 * invA + bA.x + b0 * invB + bB.x);
    w.y = f2bf(bf2f(cur.y) + a1 * invA + bA.y + b1 * invB + bB.y);
    w.z = f2bf(bf2f(cur.z) + a2 * invA + bA.z + b2 * invB + bB.z);
    w.w = f2bf(bf2f(cur.w) + a3 * invA + bA.w + b3 * invB + bB.w);
    *(ushort4*)(outx + o) = w;
}

// ---------------- cosine: one wave per row ----------------
__global__ __launch_bounds__(256) void k_cos(const float* __restrict__ ro,
                                             const float* __restrict__ pr,
                                             const int* __restrict__ types,
                                             float* __restrict__ out, int nr) {
    int row = blockIdx.x * 4 + (threadIdx.x >> 6);
    int lane = threadIdx.x & 63;
    if (row >= nr) return;
    int t = types[row];
    float2 r = ((const float2*)(ro + (size_t)row * OUTD_))[lane];
    float2 nn = ((const float2*)(pr + (size_t)row * 384 + t * OUTD_))[lane];
    float num = r.x * nn.x + r.y * nn.y;
    float d1 = r.x * r.x + r.y * r.y;
    float d2 = nn.x * nn.x + nn.y * nn.y;
    #pragma unroll
    for (int s = 1; s < 64; s <<= 1) {
        num += __shfl_xor(num, s);
        d1 += __shfl_xor(d1, s);
        d2 += __shfl_xor(d2, s);
    }
    if (lane == 0) out[row] = (num / fmaxf(sqrtf(d1) * sqrtf(d2), 1e-8f) + 1.f) * 0.5f;
}

extern "C" void kernel_launch(void* const* d_in, const int* in_sizes, int n_in,
                              void* d_out, int out_size, void* d_ws, size_t ws_size,
                              hipStream_t stream) {
    const float* x_r0 = (const float*)d_in[0];
    const float* x_p0 = (const float*)d_in[1];
    const float* x_m0 = (const float*)d_in[2];
    const int* e_src[4] = {(const int*)d_in[3], (const int*)d_in[5], (const int*)d_in[7], (const int*)d_in[9]};
    const int* e_dst[4] = {(const int*)d_in[4], (const int*)d_in[6], (const int*)d_in[8], (const int*)d_in[10]};
    const float* notes = (const float*)d_in[11];
    const int* types = (const int*)d_in[12];
    const float* Wl0 = (const float*)d_in[13];
    const float* Wr0 = (const float*)d_in[14];
    const float* bl0 = (const float*)d_in[15];
    const float* WlL = (const float*)d_in[16];
    const float* WrL = (const float*)d_in[17];
    const float* blL = (const float*)d_in[18];
    const float* Wre = (const float*)d_in[19];
    const float* bre = (const float*)d_in[20];
    const float* Wn  = (const float*)d_in[21];
    const float* bn  = (const float*)d_in[22];
    float* out = (float*)d_out;

    // ---- workspace carve ----
    uintptr_t base = (uintptr_t)d_ws;
    auto alloc = [&](size_t bytes) -> void* {
        uintptr_t p = (base + 255) & ~(uintptr_t)255;
        base = p + bytes;
        return (void*)p;
    };
    unsigned short* Rb[2] = {(unsigned short*)alloc((size_t)NR_ * 768 * 2),
                             (unsigned short*)alloc((size_t)NR_ * 768 * 2)};
    unsigned short* Pb[2] = {(unsigned short*)alloc((size_t)NP2_ * 512 * 2),
                             (unsigned short*)alloc((size_t)NP2_ * 512 * 2)};
    unsigned short* Mb[2] = {(unsigned short*)alloc((size_t)NM_ * 512 * 2),
                             (unsigned short*)alloc((size_t)NM_ * 512 * 2)};
    float* ro = (float*)alloc((size_t)NR_ * OUTD_ * 4);
    float* pr = (float*)alloc((size_t)NR_ * 384 * 4);
    unsigned short* wbf = (unsigned short*)alloc((size_t)4000000 * 2);
    int* csum = (int*)alloc(160 * 4);
    int nd[4] = {NR_, NR_, NP2_, NM_};
    Csr4 cs{};
    for (int t = 0; t < 4; ++t) {
        cs.src[t] = e_src[t]; cs.dst[t] = e_dst[t]; cs.n[t] = nd[t];
        cs.offs[t] = (int*)alloc(((size_t)nd[t] + 1) * 4);
        cs.cur[t]  = (int*)alloc((size_t)nd[t] * 4);
        cs.csr[t]  = (int*)alloc((size_t)NE_ * 4);
    }

    // ---- weight transpose+convert: concatenated B blocks, bf16 [N][K] ----
    unsigned short *BR[4], *BP[4], *BM[4], *Bre, *Bn;
    {
        WBatch wb{};
        int cnt = 0;
        size_t woff = 0;
        auto add = [&](const float* a, const float* bb, int K, int N) -> unsigned short* {
            unsigned short* dst = wbf + woff;
            woff += (size_t)K * N;
            wb.it[cnt] = WItem{a, bb, dst, K, N};
            ++cnt;
            return dst;
        };
        const size_t w0 = (size_t)EMB_ * HID_;
        const size_t wl = (size_t)HID_ * HID_;
        for (int l = 0; l < 4; ++l) {
            int K = (l == 0) ? EMB_ : HID_;
            const float* Wr_ = (l == 0) ? Wr0 : WrL + (size_t)(l - 1) * 4 * wl;
            const float* Wl_ = (l == 0) ? Wl0 : WlL + (size_t)(l - 1) * 4 * wl;
            size_t ws_ = (l == 0) ? w0 : wl;
            BR[l] = add(Wr_ + 0 * ws_, Wr_ + 1 * ws_, K, HID_);  // WrC
            add(Wl_ + 2 * ws_, nullptr, K, HID_);                 // Wl2 (r2p proj)
            add(Wl_ + 3 * ws_, nullptr, K, HID_);                 // Wl3 (r2m proj)
            BP[l] = add(Wr_ + 2 * ws_, nullptr, K, HID_);         // Wr2
            add(Wl_ + 0 * ws_, nullptr, K, HID_);                 // Wl0 (p2r proj)
            BM[l] = add(Wr_ + 3 * ws_, nullptr, K, HID_);         // Wr3
            add(Wl_ + 1 * ws_, nullptr, K, HID_);                 // Wl1 (m2r proj)
        }
        Bre = add(Wre, nullptr, HID_, OUTD_);
        Bn = add(Wn + 0 * (size_t)EMB_ * OUTD_, nullptr, EMB_, OUTD_);
        add(Wn + 1 * (size_t)EMB_ * OUTD_, nullptr, EMB_, OUTD_);
        add(Wn + 2 * (size_t)EMB_ * OUTD_, nullptr, EMB_, OUTD_);
        k_wconvT<<<dim3(128, cnt), 256, 0, stream>>>(wb);
    }

    // ---- CSR build (batched over the 4 edge types) ----
    k_zero4<<<dim3((NP2_ + 255) / 256, 4), 256, 0, stream>>>(cs);
    k_deg4<<<dim3((NE_ + 255) / 256, 4), 256, 0, stream>>>(cs);
    k_scanA<<<dim3(40, 4), 256, 0, stream>>>(cs, csum);
    k_scanB<<<1, 64, 0, stream>>>(cs, csum);
    k_scanC<<<dim3((NP2_ + 255) / 256, 4), 256, 0, stream>>>(cs, csum);
    k_scatter4<<<dim3((NE_ + 255) / 256, 4), 256, 0, stream>>>(cs);

    auto gemm_bf = [&](const unsigned short* A, int lda, const unsigned short* Bt,
                       unsigned short* C, int ldc, int M, int N, int K) {
        k_gemm<true, false><<<dim3((M + 127) / 128, N / 128), 256, 0, stream>>>(
            A, lda, Bt, C, ldc, nullptr, M, K);
    };
    auto gemm_f32a_bf = [&](const float* A, int lda, const unsigned short* Bt,
                            unsigned short* C, int ldc, int M, int N, int K) {
        k_gemm<true, true><<<dim3((M + 127) / 128, N / 128), 256, 0, stream>>>(
            A, lda, Bt, C, ldc, nullptr, M, K);
    };

    for (int l = 0; l < 4; ++l) {
        int K = (l == 0) ? EMB_ : HID_;
        unsigned short* R = Rb[l & 1];
        unsigned short* P = Pb[l & 1];
        unsigned short* M = Mb[l & 1];
        const float* bl_ = (l == 0) ? bl0 : blL + (size_t)(l - 1) * 4 * HID_;

        if (l == 0) {
            gemm_f32a_bf(x_r0, EMB_, BR[0], R, 768, NR_, 768, EMB_);
            gemm_f32a_bf(x_p0, EMB_, BP[0], P, 512, NP2_, 512, EMB_);
            gemm_f32a_bf(x_m0, EMB_, BM[0], M, 512, NM_, 512, EMB_);
        } else {
            gemm_bf(Rb[(l - 1) & 1], 768, BR[l], R, 768, NR_, 768, K);
            gemm_bf(Pb[(l - 1) & 1], 512, BP[l], P, 512, NP2_, 512, K);
            gemm_bf(Mb[(l - 1) & 1], 512, BM[l], M, 512, NM_, 512, K);
        }

        // reaction <- mean(projP) + mean(projM); protein <- mean(projR); molecule <- mean(projR2)
        k_agg2w<<<(NR_ + 3) / 4, 256, 0, stream>>>(cs.offs[0], cs.csr[0], P + 256, 512, bl_ + 0 * HID_,
                                                   cs.offs[1], cs.csr[1], M + 256, 512, bl_ + 1 * HID_,
                                                   R, 768, NR_);
        k_aggw<<<(NP2_ + 3) / 4, 256, 0, stream>>>(cs.offs[2], cs.csr[2], R + 256, 768, bl_ + 2 * HID_, P, 512, NP2_);
        k_aggw<<<(NM_ + 3) / 4, 256, 0, stream>>>(cs.offs[3], cs.csr[3], R + 512, 768, bl_ + 3 * HID_, M, 512, NM_);
    }

    // ---- final: reaction proj (f32 out) + 3 node projs (f32 out, concatenated) + cosine ----
    k_gemm<false, false><<<dim3((NR_ + 127) / 128, 1), 256, 0, stream>>>(
        Rb[1], 768, Bre, ro, OUTD_, bre, NR_, HID_);
    k_gemm<false, true><<<dim3((NR_ + 127) / 128, 3), 256, 0, stream>>>(
        notes, EMB_, Bn, pr, 384, bn, NR_, EMB_);
    k_cos<<<NR_ / 4, 256, 0, stream>>>(ro, pr, types, out, NR_);
}